// Round 8
// baseline (696.562 us; speedup 1.0000x reference)
//
#include <hip/hip_runtime.h>
#include <hip/hip_bf16.h>

// Problem constants (fixed by the reference)
constexpr int NN   = 50000;            // nodes
constexpr int EE   = 800000;           // random edges
constexpr int ETOT = EE + NN;          // + self loops
constexpr int NP   = 50048;            // rows padded to multiple of 128 (391*128)
constexpr int NBLK = (NN + 255) / 256; // 196 scan blocks
constexpr float SLOPE  = 0.2f;
constexpr float EPS_BN = 1e-5f;

typedef __attribute__((ext_vector_type(8))) short bf16x8;
typedef __attribute__((ext_vector_type(4))) float f32x4;

__device__ inline float bf2f(unsigned short u) {
    union { unsigned int i; float f; } c; c.i = ((unsigned int)u) << 16; return c.f;
}

__device__ inline void gload16(const __hip_bfloat16* g, __hip_bfloat16* l) {
    __builtin_amdgcn_global_load_lds(
        (const __attribute__((address_space(1))) unsigned int*)g,
        (__attribute__((address_space(3))) unsigned int*)l, 16, 0, 0);
}

// ---------------------------------------------------------------- CSR build

__global__ __launch_bounds__(256) void count_kernel(const int* __restrict__ ei,
                                                    int* __restrict__ cnt) {
    int j = blockIdx.x * 256 + threadIdx.x;
    if (j >= ETOT) return;
    int dst = (j < EE) ? ei[EE + j] : (j - EE);
    atomicAdd(&cnt[dst], 1);
}

__global__ __launch_bounds__(256) void scanA_kernel(const int* __restrict__ cnt,
                                                    int* __restrict__ off,
                                                    int* __restrict__ bsum) {
    int b = blockIdx.x, t = threadIdx.x;
    int i = b * 256 + t;
    int v = (i < NN) ? cnt[i] : 0;
    int lane = t & 63, w = t >> 6;
    int x = v;
    #pragma unroll
    for (int o = 1; o < 64; o <<= 1) { int y = __shfl_up(x, o); if (lane >= o) x += y; }
    __shared__ int ws[4];
    if (lane == 63) ws[w] = x;
    __syncthreads();
    int wo = 0;
    for (int k = 0; k < w; ++k) wo += ws[k];
    int incl = x + wo;
    if (i < NN) off[i] = incl - v;
    if (t == 255) bsum[b] = incl;
}

__global__ __launch_bounds__(256) void scanB_kernel(const int* __restrict__ bsum,
                                                    int* __restrict__ bexc,
                                                    int* __restrict__ off) {
    int t = threadIdx.x;
    int v = (t < NBLK) ? bsum[t] : 0;
    int lane = t & 63, w = t >> 6;
    int x = v;
    #pragma unroll
    for (int o = 1; o < 64; o <<= 1) { int y = __shfl_up(x, o); if (lane >= o) x += y; }
    __shared__ int ws[4];
    if (lane == 63) ws[w] = x;
    __syncthreads();
    int wo = 0;
    for (int k = 0; k < w; ++k) wo += ws[k];
    int incl = x + wo;
    if (t < NBLK) bexc[t] = incl - v;
    if (t == 255) off[NN] = incl;
}

__global__ __launch_bounds__(256) void scanC_kernel(const int* __restrict__ bexc,
                                                    int* __restrict__ off,
                                                    int* __restrict__ cur) {
    int i = blockIdx.x * 256 + threadIdx.x;
    if (i >= NN) return;
    int v = off[i] + bexc[blockIdx.x];
    off[i] = v;
    cur[i] = v;
}

__global__ __launch_bounds__(256) void fill_kernel(const int* __restrict__ ei,
                                                   int* __restrict__ cursor,
                                                   int* __restrict__ ssrc) {
    int j = blockIdx.x * 256 + threadIdx.x;
    if (j >= ETOT) return;
    int src, dst;
    if (j < EE) { src = ei[j]; dst = ei[EE + j]; }
    else        { src = dst = j - EE; }
    int pos = atomicAdd(&cursor[dst], 1);
    ssrc[pos] = src;
}

// ---------------------------------------------------------------- layer-1 casts (fused)
constexpr int XB = (int)(((long)NP * 128 / 8 + 255) / 256);
__global__ __launch_bounds__(256) void castwx_kernel(const float* __restrict__ X,
                                                     const float* __restrict__ W,
                                                     __hip_bfloat16* __restrict__ Xbf,
                                                     __hip_bfloat16* __restrict__ WT) {
    int b = blockIdx.x;
    if (b < XB) {
        long e0 = ((long)b * 256 + threadIdx.x) * 8;
        if (e0 >= (long)NP * 128) return;
        int row = (int)(e0 / 128);
        __hip_bfloat16 o[8];
        if (row < NN) {
            float4 v0 = *reinterpret_cast<const float4*>(X + e0);
            float4 v1 = *reinterpret_cast<const float4*>(X + e0 + 4);
            o[0] = __float2bfloat16(v0.x); o[1] = __float2bfloat16(v0.y);
            o[2] = __float2bfloat16(v0.z); o[3] = __float2bfloat16(v0.w);
            o[4] = __float2bfloat16(v1.x); o[5] = __float2bfloat16(v1.y);
            o[6] = __float2bfloat16(v1.z); o[7] = __float2bfloat16(v1.w);
        } else {
            for (int j = 0; j < 8; ++j) o[j] = __float2bfloat16(0.f);
        }
        *reinterpret_cast<bf16x8*>(Xbf + e0) = *reinterpret_cast<bf16x8*>(o);
    } else {
        int i = (b - XB) * 256 + threadIdx.x;
        int c = i / 128, k = i % 128;
        WT[i] = __float2bfloat16(W[(size_t)k * 256 + c]);
    }
}

// fold BN (from raw sums) + transpose next-layer W
template <int WOUT>
__global__ __launch_bounds__(256) void foldw_kernel(const float* __restrict__ W,
                                                    const float* __restrict__ sums,
                                                    const float* __restrict__ gamma,
                                                    const float* __restrict__ beta,
                                                    __hip_bfloat16* __restrict__ WTp,
                                                    float* __restrict__ bb) {
    int c = blockIdx.x, k = threadIdx.x;
    float mean = sums[k] / (float)NN;
    float var  = sums[256 + k] / (float)NN - mean * mean;
    float inv  = rsqrtf(var + EPS_BN);
    float sc   = gamma[k] * inv;
    float sh   = beta[k] - mean * sc;
    float w = W[(size_t)k * WOUT + c];
    WTp[(size_t)c * 256 + k] = __float2bfloat16(sc * w);
    float p = sh * w;
    #pragma unroll
    for (int o = 1; o < 64; o <<= 1) p += __shfl_xor(p, o);
    __shared__ float ps[4];
    if ((k & 63) == 0) ps[k >> 6] = p;
    __syncthreads();
    if (k == 0) bb[c] = ps[0] + ps[1] + ps[2] + ps[3];
}

// ---------------------------------------------------------------- MFMA GEMM + fused al_src/al_dst
// H output is written in PANEL layout: panel p holds cols [p*PW, (p+1)*PW) for
// all rows contiguously (PW = 32 for WOUT=256, 16 for WOUT=128). Each panel is
// 3.2/1.6 MB -> fits a single XCD L2 for the sharded attn gather.
template <int FIN, int WOUT, bool FOLD>
__global__ __launch_bounds__(256) void mgemm_kernel(const __hip_bfloat16* __restrict__ A,
                                                    const __hip_bfloat16* __restrict__ BT,
                                                    const float* __restrict__ bb,
                                                    const float* __restrict__ a_src,
                                                    const float* __restrict__ a_dst,
                                                    __hip_bfloat16* __restrict__ Hpan,
                                                    float* __restrict__ als,
                                                    float* __restrict__ ald) {
    constexpr int PW = (WOUT == 256) ? 32 : 16;
    __shared__ __hip_bfloat16 As[128 * 32];
    __shared__ __hip_bfloat16 Bs[128 * 32];
    int t = threadIdx.x;
    int lane = t & 63, w = t >> 6;
    int row0 = blockIdx.x * 128;
    int col0 = blockIdx.y * 128;
    int wr = w >> 1, wc = w & 1;

    f32x4 acc[4][4];
    #pragma unroll
    for (int m = 0; m < 4; ++m)
        #pragma unroll
        for (int n = 0; n < 4; ++n) acc[m][n] = (f32x4){0.f, 0.f, 0.f, 0.f};

    int srow = w * 32 + (lane >> 2);
    int sbc  = (lane & 3) * 8;
    const __hip_bfloat16* gA0 = A  + (size_t)(row0 + srow)      * FIN + sbc;
    const __hip_bfloat16* gA1 = A  + (size_t)(row0 + srow + 16) * FIN + sbc;
    const __hip_bfloat16* gB0 = BT + (size_t)(col0 + srow)      * FIN + sbc;
    const __hip_bfloat16* gB1 = BT + (size_t)(col0 + srow + 16) * FIN + sbc;
    __hip_bfloat16* lA0 = As + w * 1024;
    __hip_bfloat16* lA1 = As + w * 1024 + 512;
    __hip_bfloat16* lB0 = Bs + w * 1024;
    __hip_bfloat16* lB1 = Bs + w * 1024 + 512;

    int rA = (wr * 64 + (lane & 15)) * 32 + (lane >> 4) * 8;
    int rB = (wc * 64 + (lane & 15)) * 32 + (lane >> 4) * 8;

    for (int k0 = 0; k0 < FIN; k0 += 32) {
        gload16(gA0 + k0, lA0);
        gload16(gA1 + k0, lA1);
        gload16(gB0 + k0, lB0);
        gload16(gB1 + k0, lB1);
        __syncthreads();
        bf16x8 af[4], bfr[4];
        #pragma unroll
        for (int m = 0; m < 4; ++m) af[m]  = *reinterpret_cast<const bf16x8*>(As + rA + m * 16 * 32);
        #pragma unroll
        for (int n = 0; n < 4; ++n) bfr[n] = *reinterpret_cast<const bf16x8*>(Bs + rB + n * 16 * 32);
        #pragma unroll
        for (int m = 0; m < 4; ++m)
            #pragma unroll
            for (int n = 0; n < 4; ++n)
                acc[m][n] = __builtin_amdgcn_mfma_f32_16x16x32_bf16(af[m], bfr[n], acc[m][n], 0, 0, 0);
        __syncthreads();
    }

    int cih = lane & 15;

    if constexpr (FOLD) {
        #pragma unroll
        for (int n = 0; n < 4; ++n) {
            float badd = bb[col0 + wc * 64 + n * 16 + cih];
            #pragma unroll
            for (int m = 0; m < 4; ++m)
                #pragma unroll
                for (int j = 0; j < 4; ++j) acc[m][n][j] += badd;
        }
    }

    float asv[4], adv[4];
    int headw = 0;
    if constexpr (WOUT == 256) {
        headw = (col0 >> 6) + wc;
        #pragma unroll
        for (int n = 0; n < 4; ++n) {
            asv[n] = a_src[headw * 64 + n * 16 + cih];
            adv[n] = a_dst[headw * 64 + n * 16 + cih];
        }
    } else {
        #pragma unroll
        for (int n = 0; n < 4; ++n) {
            int hh = wc * 2 + (n >> 1);
            asv[n] = a_src[hh * 32 + (n & 1) * 16 + cih];
            adv[n] = a_dst[hh * 32 + (n & 1) * 16 + cih];
        }
    }

    #pragma unroll
    for (int m = 0; m < 4; ++m) {
        #pragma unroll
        for (int j = 0; j < 4; ++j) {
            int r = row0 + wr * 64 + m * 16 + (lane >> 4) * 4 + j;
            if constexpr (WOUT == 256) {
                float vs = acc[m][0][j] * asv[0] + acc[m][1][j] * asv[1]
                         + acc[m][2][j] * asv[2] + acc[m][3][j] * asv[3];
                float vd = acc[m][0][j] * adv[0] + acc[m][1][j] * adv[1]
                         + acc[m][2][j] * adv[2] + acc[m][3][j] * adv[3];
                #pragma unroll
                for (int o = 1; o < 16; o <<= 1) {
                    vs += __shfl_xor(vs, o);
                    vd += __shfl_xor(vd, o);
                }
                if (cih == 0) {
                    als[(size_t)r * 4 + headw] = vs;
                    ald[(size_t)r * 4 + headw] = vd;
                }
            } else {
                float vs0 = acc[m][0][j] * asv[0] + acc[m][1][j] * asv[1];
                float vs1 = acc[m][2][j] * asv[2] + acc[m][3][j] * asv[3];
                float vd0 = acc[m][0][j] * adv[0] + acc[m][1][j] * adv[1];
                float vd1 = acc[m][2][j] * adv[2] + acc[m][3][j] * adv[3];
                #pragma unroll
                for (int o = 1; o < 16; o <<= 1) {
                    vs0 += __shfl_xor(vs0, o); vs1 += __shfl_xor(vs1, o);
                    vd0 += __shfl_xor(vd0, o); vd1 += __shfl_xor(vd1, o);
                }
                if (cih == 0) {
                    als[(size_t)r * 4 + wc * 2]     = vs0;
                    als[(size_t)r * 4 + wc * 2 + 1] = vs1;
                    ald[(size_t)r * 4 + wc * 2]     = vd0;
                    ald[(size_t)r * 4 + wc * 2 + 1] = vd1;
                }
            }
        }
    }

    // store H in panel layout
    #pragma unroll
    for (int n = 0; n < 4; ++n) {
        int c = col0 + wc * 64 + n * 16 + cih;
        int p = c / PW;
        int cw = c % PW;
        #pragma unroll
        for (int m = 0; m < 4; ++m) {
            int r = row0 + wr * 64 + m * 16 + (lane >> 4) * 4;
            #pragma unroll
            for (int j = 0; j < 4; ++j)
                Hpan[(size_t)p * NP * PW + (size_t)(r + j) * PW + cw] =
                    __float2bfloat16(acc[m][n][j]);
        }
    }
}

// ---------------------------------------------------------------- XCD-sharded attn
// grid = (8, NN/16). slice = blockIdx.x -> lands on XCD (slice) under round-robin.
// Panel s (32 cols, 3.2 MB) becomes L2-resident on its XCD.
// Wave layout: 16 clusters x 4 lanes; cluster handles one edge; lane covers 8 cols.
__global__ __launch_bounds__(256) void attn256s_kernel(const __hip_bfloat16* __restrict__ Hpan,
                                                       const int* __restrict__ off,
                                                       const int* __restrict__ ssrc,
                                                       const float* __restrict__ als,
                                                       const float* __restrict__ ald,
                                                       const float* __restrict__ bias,
                                                       __hip_bfloat16* __restrict__ Out) {
    int s    = blockIdx.x;               // panel / slice
    int wv   = threadIdx.x >> 6;
    int lane = threadIdx.x & 63;
    int cl   = lane >> 2;                // edge cluster 0..15
    int sub  = lane & 3;                 // 8-col segment within slice
    int head = s >> 1;                   // 32-col slice sits inside one head (C=64)
    const __hip_bfloat16* Hp = Hpan + (size_t)s * NP * 32;

    float4 bia0 = *reinterpret_cast<const float4*>(bias + s * 32 + sub * 8);
    float4 bia1 = *reinterpret_cast<const float4*>(bias + s * 32 + sub * 8 + 4);

    #pragma unroll
    for (int k = 0; k < 4; ++k) {
        int d = blockIdx.y * 16 + wv * 4 + k;
        int e0 = off[d], e1 = off[d + 1];
        float aldh = ald[(size_t)d * 4 + head];

        float acc[8];
        #pragma unroll
        for (int c = 0; c < 8; ++c) acc[c] = 0.f;
        float den = 0.f;

        for (int j = e0 + cl; j < e1; j += 16) {
            int src = ssrc[j];
            float x = als[(size_t)src * 4 + head] + aldh;
            x = (x > 0.f) ? x : SLOPE * x;
            float wgt = __expf(x);
            den += wgt;
            bf16x8 v = *reinterpret_cast<const bf16x8*>(Hp + (size_t)src * 32 + sub * 8);
            #pragma unroll
            for (int c = 0; c < 8; ++c) acc[c] += wgt * bf2f((unsigned short)v[c]);
        }

        #pragma unroll
        for (int o = 4; o < 64; o <<= 1) {
            #pragma unroll
            for (int c = 0; c < 8; ++c) acc[c] += __shfl_xor(acc[c], o);
            den += __shfl_xor(den, o);
        }
        float inv = 1.f / (den + 1e-16f);

        if (cl == 0) {
            __hip_bfloat16 ob[8];
            ob[0] = __float2bfloat16(fmaxf(acc[0] * inv + bia0.x, 0.f));
            ob[1] = __float2bfloat16(fmaxf(acc[1] * inv + bia0.y, 0.f));
            ob[2] = __float2bfloat16(fmaxf(acc[2] * inv + bia0.z, 0.f));
            ob[3] = __float2bfloat16(fmaxf(acc[3] * inv + bia0.w, 0.f));
            ob[4] = __float2bfloat16(fmaxf(acc[4] * inv + bia1.x, 0.f));
            ob[5] = __float2bfloat16(fmaxf(acc[5] * inv + bia1.y, 0.f));
            ob[6] = __float2bfloat16(fmaxf(acc[6] * inv + bia1.z, 0.f));
            ob[7] = __float2bfloat16(fmaxf(acc[7] * inv + bia1.w, 0.f));
            *reinterpret_cast<bf16x8*>(Out + (size_t)d * 256 + s * 32 + sub * 8) =
                *reinterpret_cast<bf16x8*>(ob);
        }
    }
}

// Final layer: 8 slices x 16 cols (panel 1.6 MB). 32 clusters x 2 lanes. f32 out.
__global__ __launch_bounds__(256) void attn128s_kernel(const __hip_bfloat16* __restrict__ Hpan,
                                                       const int* __restrict__ off,
                                                       const int* __restrict__ ssrc,
                                                       const float* __restrict__ als,
                                                       const float* __restrict__ ald,
                                                       const float* __restrict__ bias,
                                                       float* __restrict__ Out) {
    int s    = blockIdx.x;
    int wv   = threadIdx.x >> 6;
    int lane = threadIdx.x & 63;
    int cl   = lane >> 1;                // edge cluster 0..31
    int sub  = lane & 1;                 // 8-col segment within slice
    int head = s >> 1;                   // 16-col slice inside one head (C=32)
    const __hip_bfloat16* Hp = Hpan + (size_t)s * NP * 16;

    float4 bia0 = *reinterpret_cast<const float4*>(bias + s * 16 + sub * 8);
    float4 bia1 = *reinterpret_cast<const float4*>(bias + s * 16 + sub * 8 + 4);

    #pragma unroll
    for (int k = 0; k < 4; ++k) {
        int d = blockIdx.y * 16 + wv * 4 + k;
        int e0 = off[d], e1 = off[d + 1];
        float aldh = ald[(size_t)d * 4 + head];

        float acc[8];
        #pragma unroll
        for (int c = 0; c < 8; ++c) acc[c] = 0.f;
        float den = 0.f;

        for (int j = e0 + cl; j < e1; j += 32) {
            int src = ssrc[j];
            float x = als[(size_t)src * 4 + head] + aldh;
            x = (x > 0.f) ? x : SLOPE * x;
            float wgt = __expf(x);
            den += wgt;
            bf16x8 v = *reinterpret_cast<const bf16x8*>(Hp + (size_t)src * 16 + sub * 8);
            #pragma unroll
            for (int c = 0; c < 8; ++c) acc[c] += wgt * bf2f((unsigned short)v[c]);
        }

        #pragma unroll
        for (int o = 2; o < 64; o <<= 1) {
            #pragma unroll
            for (int c = 0; c < 8; ++c) acc[c] += __shfl_xor(acc[c], o);
            den += __shfl_xor(den, o);
        }
        float inv = 1.f / (den + 1e-16f);

        if (cl == 0) {
            float* op = Out + (size_t)d * 128 + s * 16 + sub * 8;
            *reinterpret_cast<float4*>(op) = make_float4(
                fmaxf(acc[0] * inv + bia0.x, 0.f), fmaxf(acc[1] * inv + bia0.y, 0.f),
                fmaxf(acc[2] * inv + bia0.z, 0.f), fmaxf(acc[3] * inv + bia0.w, 0.f));
            *reinterpret_cast<float4*>(op + 4) = make_float4(
                fmaxf(acc[4] * inv + bia1.x, 0.f), fmaxf(acc[5] * inv + bia1.y, 0.f),
                fmaxf(acc[6] * inv + bia1.z, 0.f), fmaxf(acc[7] * inv + bia1.w, 0.f));
        }
    }
}

// ---------------------------------------------------------------- batch norm (bf16 input)
__global__ __launch_bounds__(256) void bnstats_kernel(const __hip_bfloat16* __restrict__ X,
                                                      float* __restrict__ sums) {
    int c  = threadIdx.x;
    int r0 = blockIdx.x * 200;
    float s = 0.f, q = 0.f;
    for (int r = r0; r < r0 + 200; ++r) {
        float v = bf2f(*(const unsigned short*)(X + (size_t)r * 256 + c));
        s += v; q += v * v;
    }
    atomicAdd(&sums[c], s);
    atomicAdd(&sums[256 + c], q);
}

// ---------------------------------------------------------------- launch

extern "C" void kernel_launch(void* const* d_in, const int* in_sizes, int n_in,
                              void* d_out, int out_size, void* d_ws, size_t ws_size,
                              hipStream_t stream) {
    const float* x      = (const float*)d_in[0];
    const int*   ei     = (const int*)d_in[1];
    const float* W1     = (const float*)d_in[2];
    const float* a_s1   = (const float*)d_in[3];
    const float* a_d1   = (const float*)d_in[4];
    const float* b1     = (const float*)d_in[5];
    const float* W2     = (const float*)d_in[6];
    const float* a_s2   = (const float*)d_in[7];
    const float* a_d2   = (const float*)d_in[8];
    const float* b2     = (const float*)d_in[9];
    const float* W3     = (const float*)d_in[10];
    const float* a_s3   = (const float*)d_in[11];
    const float* a_d3   = (const float*)d_in[12];
    const float* b3     = (const float*)d_in[13];
    const float* gamma1 = (const float*)d_in[14];
    const float* beta1  = (const float*)d_in[15];
    const float* gamma2 = (const float*)d_in[16];
    const float* beta2  = (const float*)d_in[17];

    char* ws = (char*)d_ws;
    size_t o = 0;
    auto alloc = [&](size_t bytes) -> void* {
        void* p = ws + o;
        o = (o + bytes + 255) & ~size_t(255);
        return p;
    };
    __hip_bfloat16*  Abf  = (__hip_bfloat16*)alloc((size_t)NP * 256 * 2);
    __hip_bfloat16*  Hbf  = (__hip_bfloat16*)alloc((size_t)NP * 256 * 2);
    __hip_bfloat16*  Xbf  = (__hip_bfloat16*)alloc((size_t)NP * 128 * 2);
    __hip_bfloat16*  WT1  = (__hip_bfloat16*)alloc((size_t)256 * 128 * 2);
    __hip_bfloat16*  WT2  = (__hip_bfloat16*)alloc((size_t)256 * 256 * 2);
    __hip_bfloat16*  WT3  = (__hip_bfloat16*)alloc((size_t)128 * 256 * 2);
    float* bb2   = (float*)alloc(256 * 4);
    float* bb3   = (float*)alloc(128 * 4);
    float* als   = (float*)alloc((size_t)NP * 4 * 4);
    float* ald   = (float*)alloc((size_t)NP * 4 * 4);
    float* sums  = (float*)alloc(512 * 4);
    int*   off   = (int*)alloc((size_t)(NN + 1) * 4);
    int*   cur   = (int*)alloc((size_t)NN * 4);
    int*   cnt   = (int*)alloc((size_t)NN * 4);
    int*   bsum  = (int*)alloc((size_t)NBLK * 4);
    int*   bexc  = (int*)alloc((size_t)NBLK * 4);
    int*   ssrc  = (int*)alloc((size_t)ETOT * 4);
    (void)ws_size; (void)in_sizes; (void)n_in; (void)out_size;

    const int EB = (ETOT + 255) / 256;

    // --- CSR build (shared by all 3 layers)
    hipMemsetAsync(cnt, 0, (size_t)NN * 4, stream);
    count_kernel<<<EB, 256, 0, stream>>>(ei, cnt);
    scanA_kernel<<<NBLK, 256, 0, stream>>>(cnt, off, bsum);
    scanB_kernel<<<1, 256, 0, stream>>>(bsum, bexc, off);
    scanC_kernel<<<NBLK, 256, 0, stream>>>(bexc, off, cur);
    fill_kernel<<<EB, 256, 0, stream>>>(ei, cur, ssrc);

    // --- layer 1
    castwx_kernel<<<XB + 128, 256, 0, stream>>>(x, W1, Xbf, WT1);
    mgemm_kernel<128, 256, false><<<dim3(NP / 128, 2), 256, 0, stream>>>(
        Xbf, WT1, nullptr, a_s1, a_d1, Hbf, als, ald);
    attn256s_kernel<<<dim3(8, NN / 16), 256, 0, stream>>>(Hbf, off, ssrc, als, ald, b1, Abf);

    hipMemsetAsync(sums, 0, 512 * 4, stream);
    bnstats_kernel<<<250, 256, 0, stream>>>(Abf, sums);
    foldw_kernel<256><<<256, 256, 0, stream>>>(W2, sums, gamma1, beta1, WT2, bb2);

    // --- layer 2 (BN folded into WT2/bb2)
    mgemm_kernel<256, 256, true><<<dim3(NP / 128, 2), 256, 0, stream>>>(
        Abf, WT2, bb2, a_s2, a_d2, Hbf, als, ald);
    attn256s_kernel<<<dim3(8, NN / 16), 256, 0, stream>>>(Hbf, off, ssrc, als, ald, b2, Abf);

    hipMemsetAsync(sums, 0, 512 * 4, stream);
    bnstats_kernel<<<250, 256, 0, stream>>>(Abf, sums);
    foldw_kernel<128><<<128, 256, 0, stream>>>(W3, sums, gamma2, beta2, WT3, bb3);

    // --- layer 3 (BN folded into WT3/bb3), f32 output
    mgemm_kernel<256, 128, true><<<dim3(NP / 128, 1), 256, 0, stream>>>(
        Abf, WT3, bb3, a_s3, a_d3, Hbf, als, ald);
    attn128s_kernel<<<dim3(8, NN / 16), 256, 0, stream>>>(Hbf, off, ssrc, als, ald, b3, (float*)d_out);
}

// Round 9
// 608.416 us; speedup vs baseline: 1.1449x; 1.1449x over previous
//
#include <hip/hip_runtime.h>
#include <hip/hip_bf16.h>

// Problem constants (fixed by the reference)
constexpr int NN   = 50000;            // nodes
constexpr int EE   = 800000;           // random edges
constexpr int ETOT = EE + NN;          // + self loops
constexpr int NP   = 50048;            // rows padded to multiple of 128 (391*128)
constexpr int NBLK = (NN + 255) / 256; // 196 scan blocks
constexpr float SLOPE  = 0.2f;
constexpr float EPS_BN = 1e-5f;

typedef __attribute__((ext_vector_type(8))) short bf16x8;
typedef __attribute__((ext_vector_type(4))) float f32x4;

__device__ inline float bf2f(unsigned short u) {
    union { unsigned int i; float f; } c; c.i = ((unsigned int)u) << 16; return c.f;
}

__device__ inline void gload16(const __hip_bfloat16* g, __hip_bfloat16* l) {
    __builtin_amdgcn_global_load_lds(
        (const __attribute__((address_space(1))) unsigned int*)g,
        (__attribute__((address_space(3))) unsigned int*)l, 16, 0, 0);
}

// ---------------------------------------------------------------- CSR build

__global__ __launch_bounds__(256) void count_kernel(const int* __restrict__ ei,
                                                    int* __restrict__ cnt) {
    int j = blockIdx.x * 256 + threadIdx.x;
    if (j >= ETOT) return;
    int dst = (j < EE) ? ei[EE + j] : (j - EE);
    atomicAdd(&cnt[dst], 1);
}

__global__ __launch_bounds__(256) void scanA_kernel(const int* __restrict__ cnt,
                                                    int* __restrict__ off,
                                                    int* __restrict__ bsum) {
    int b = blockIdx.x, t = threadIdx.x;
    int i = b * 256 + t;
    int v = (i < NN) ? cnt[i] : 0;
    int lane = t & 63, w = t >> 6;
    int x = v;
    #pragma unroll
    for (int o = 1; o < 64; o <<= 1) { int y = __shfl_up(x, o); if (lane >= o) x += y; }
    __shared__ int ws[4];
    if (lane == 63) ws[w] = x;
    __syncthreads();
    int wo = 0;
    for (int k = 0; k < w; ++k) wo += ws[k];
    int incl = x + wo;
    if (i < NN) off[i] = incl - v;
    if (t == 255) bsum[b] = incl;
}

__global__ __launch_bounds__(256) void scanB_kernel(const int* __restrict__ bsum,
                                                    int* __restrict__ bexc,
                                                    int* __restrict__ off) {
    int t = threadIdx.x;
    int v = (t < NBLK) ? bsum[t] : 0;
    int lane = t & 63, w = t >> 6;
    int x = v;
    #pragma unroll
    for (int o = 1; o < 64; o <<= 1) { int y = __shfl_up(x, o); if (lane >= o) x += y; }
    __shared__ int ws[4];
    if (lane == 63) ws[w] = x;
    __syncthreads();
    int wo = 0;
    for (int k = 0; k < w; ++k) wo += ws[k];
    int incl = x + wo;
    if (t < NBLK) bexc[t] = incl - v;
    if (t == 255) off[NN] = incl;
}

__global__ __launch_bounds__(256) void scanC_kernel(const int* __restrict__ bexc,
                                                    int* __restrict__ off,
                                                    int* __restrict__ cur) {
    int i = blockIdx.x * 256 + threadIdx.x;
    if (i >= NN) return;
    int v = off[i] + bexc[blockIdx.x];
    off[i] = v;
    cur[i] = v;
}

__global__ __launch_bounds__(256) void fill_kernel(const int* __restrict__ ei,
                                                   int* __restrict__ cursor,
                                                   int* __restrict__ ssrc) {
    int j = blockIdx.x * 256 + threadIdx.x;
    if (j >= ETOT) return;
    int src, dst;
    if (j < EE) { src = ei[j]; dst = ei[EE + j]; }
    else        { src = dst = j - EE; }
    int pos = atomicAdd(&cursor[dst], 1);
    ssrc[pos] = src;
}

// ---------------------------------------------------------------- layer-1 casts (fused)
constexpr int XB = (int)(((long)NP * 128 / 8 + 255) / 256);
__global__ __launch_bounds__(256) void castwx_kernel(const float* __restrict__ X,
                                                     const float* __restrict__ W,
                                                     __hip_bfloat16* __restrict__ Xbf,
                                                     __hip_bfloat16* __restrict__ WT) {
    int b = blockIdx.x;
    if (b < XB) {
        long e0 = ((long)b * 256 + threadIdx.x) * 8;
        if (e0 >= (long)NP * 128) return;
        int row = (int)(e0 / 128);
        __hip_bfloat16 o[8];
        if (row < NN) {
            float4 v0 = *reinterpret_cast<const float4*>(X + e0);
            float4 v1 = *reinterpret_cast<const float4*>(X + e0 + 4);
            o[0] = __float2bfloat16(v0.x); o[1] = __float2bfloat16(v0.y);
            o[2] = __float2bfloat16(v0.z); o[3] = __float2bfloat16(v0.w);
            o[4] = __float2bfloat16(v1.x); o[5] = __float2bfloat16(v1.y);
            o[6] = __float2bfloat16(v1.z); o[7] = __float2bfloat16(v1.w);
        } else {
            for (int j = 0; j < 8; ++j) o[j] = __float2bfloat16(0.f);
        }
        *reinterpret_cast<bf16x8*>(Xbf + e0) = *reinterpret_cast<bf16x8*>(o);
    } else {
        int i = (b - XB) * 256 + threadIdx.x;
        int c = i / 128, k = i % 128;
        WT[i] = __float2bfloat16(W[(size_t)k * 256 + c]);
    }
}

// fold BN (from raw sums) + transpose next-layer W
template <int WOUT>
__global__ __launch_bounds__(256) void foldw_kernel(const float* __restrict__ W,
                                                    const float* __restrict__ sums,
                                                    const float* __restrict__ gamma,
                                                    const float* __restrict__ beta,
                                                    __hip_bfloat16* __restrict__ WTp,
                                                    float* __restrict__ bb) {
    int c = blockIdx.x, k = threadIdx.x;
    float mean = sums[k] / (float)NN;
    float var  = sums[256 + k] / (float)NN - mean * mean;
    float inv  = rsqrtf(var + EPS_BN);
    float sc   = gamma[k] * inv;
    float sh   = beta[k] - mean * sc;
    float w = W[(size_t)k * WOUT + c];
    WTp[(size_t)c * 256 + k] = __float2bfloat16(sc * w);
    float p = sh * w;
    #pragma unroll
    for (int o = 1; o < 64; o <<= 1) p += __shfl_xor(p, o);
    __shared__ float ps[4];
    if ((k & 63) == 0) ps[k >> 6] = p;
    __syncthreads();
    if (k == 0) bb[c] = ps[0] + ps[1] + ps[2] + ps[3];
}

// ---------------------------------------------------------------- MFMA GEMM + fused al_src/al_dst
// H written in PANEL layout: panel p = cols [p*32,(p+1)*32) contiguous over rows.
// Panel = NP*32*2B = 3.2 MB -> fits one XCD L2.
template <int FIN, int WOUT, bool FOLD>
__global__ __launch_bounds__(256) void mgemm_kernel(const __hip_bfloat16* __restrict__ A,
                                                    const __hip_bfloat16* __restrict__ BT,
                                                    const float* __restrict__ bb,
                                                    const float* __restrict__ a_src,
                                                    const float* __restrict__ a_dst,
                                                    __hip_bfloat16* __restrict__ Hpan,
                                                    float* __restrict__ als,
                                                    float* __restrict__ ald) {
    __shared__ __hip_bfloat16 As[128 * 32];
    __shared__ __hip_bfloat16 Bs[128 * 32];
    int t = threadIdx.x;
    int lane = t & 63, w = t >> 6;
    int row0 = blockIdx.x * 128;
    int col0 = blockIdx.y * 128;
    int wr = w >> 1, wc = w & 1;

    f32x4 acc[4][4];
    #pragma unroll
    for (int m = 0; m < 4; ++m)
        #pragma unroll
        for (int n = 0; n < 4; ++n) acc[m][n] = (f32x4){0.f, 0.f, 0.f, 0.f};

    int srow = w * 32 + (lane >> 2);
    int sbc  = (lane & 3) * 8;
    const __hip_bfloat16* gA0 = A  + (size_t)(row0 + srow)      * FIN + sbc;
    const __hip_bfloat16* gA1 = A  + (size_t)(row0 + srow + 16) * FIN + sbc;
    const __hip_bfloat16* gB0 = BT + (size_t)(col0 + srow)      * FIN + sbc;
    const __hip_bfloat16* gB1 = BT + (size_t)(col0 + srow + 16) * FIN + sbc;
    __hip_bfloat16* lA0 = As + w * 1024;
    __hip_bfloat16* lA1 = As + w * 1024 + 512;
    __hip_bfloat16* lB0 = Bs + w * 1024;
    __hip_bfloat16* lB1 = Bs + w * 1024 + 512;

    int rA = (wr * 64 + (lane & 15)) * 32 + (lane >> 4) * 8;
    int rB = (wc * 64 + (lane & 15)) * 32 + (lane >> 4) * 8;

    for (int k0 = 0; k0 < FIN; k0 += 32) {
        gload16(gA0 + k0, lA0);
        gload16(gA1 + k0, lA1);
        gload16(gB0 + k0, lB0);
        gload16(gB1 + k0, lB1);
        __syncthreads();
        bf16x8 af[4], bfr[4];
        #pragma unroll
        for (int m = 0; m < 4; ++m) af[m]  = *reinterpret_cast<const bf16x8*>(As + rA + m * 16 * 32);
        #pragma unroll
        for (int n = 0; n < 4; ++n) bfr[n] = *reinterpret_cast<const bf16x8*>(Bs + rB + n * 16 * 32);
        #pragma unroll
        for (int m = 0; m < 4; ++m)
            #pragma unroll
            for (int n = 0; n < 4; ++n)
                acc[m][n] = __builtin_amdgcn_mfma_f32_16x16x32_bf16(af[m], bfr[n], acc[m][n], 0, 0, 0);
        __syncthreads();
    }

    int cih = lane & 15;

    if constexpr (FOLD) {
        #pragma unroll
        for (int n = 0; n < 4; ++n) {
            float badd = bb[col0 + wc * 64 + n * 16 + cih];
            #pragma unroll
            for (int m = 0; m < 4; ++m)
                #pragma unroll
                for (int j = 0; j < 4; ++j) acc[m][n][j] += badd;
        }
    }

    float asv[4], adv[4];
    int headw = 0;
    if constexpr (WOUT == 256) {
        headw = (col0 >> 6) + wc;
        #pragma unroll
        for (int n = 0; n < 4; ++n) {
            asv[n] = a_src[headw * 64 + n * 16 + cih];
            adv[n] = a_dst[headw * 64 + n * 16 + cih];
        }
    } else {
        #pragma unroll
        for (int n = 0; n < 4; ++n) {
            int hh = wc * 2 + (n >> 1);
            asv[n] = a_src[hh * 32 + (n & 1) * 16 + cih];
            adv[n] = a_dst[hh * 32 + (n & 1) * 16 + cih];
        }
    }

    #pragma unroll
    for (int m = 0; m < 4; ++m) {
        #pragma unroll
        for (int j = 0; j < 4; ++j) {
            int r = row0 + wr * 64 + m * 16 + (lane >> 4) * 4 + j;
            if constexpr (WOUT == 256) {
                float vs = acc[m][0][j] * asv[0] + acc[m][1][j] * asv[1]
                         + acc[m][2][j] * asv[2] + acc[m][3][j] * asv[3];
                float vd = acc[m][0][j] * adv[0] + acc[m][1][j] * adv[1]
                         + acc[m][2][j] * adv[2] + acc[m][3][j] * adv[3];
                #pragma unroll
                for (int o = 1; o < 16; o <<= 1) {
                    vs += __shfl_xor(vs, o);
                    vd += __shfl_xor(vd, o);
                }
                if (cih == 0) {
                    als[(size_t)r * 4 + headw] = vs;
                    ald[(size_t)r * 4 + headw] = vd;
                }
            } else {
                float vs0 = acc[m][0][j] * asv[0] + acc[m][1][j] * asv[1];
                float vs1 = acc[m][2][j] * asv[2] + acc[m][3][j] * asv[3];
                float vd0 = acc[m][0][j] * adv[0] + acc[m][1][j] * adv[1];
                float vd1 = acc[m][2][j] * adv[2] + acc[m][3][j] * adv[3];
                #pragma unroll
                for (int o = 1; o < 16; o <<= 1) {
                    vs0 += __shfl_xor(vs0, o); vs1 += __shfl_xor(vs1, o);
                    vd0 += __shfl_xor(vd0, o); vd1 += __shfl_xor(vd1, o);
                }
                if (cih == 0) {
                    als[(size_t)r * 4 + wc * 2]     = vs0;
                    als[(size_t)r * 4 + wc * 2 + 1] = vs1;
                    ald[(size_t)r * 4 + wc * 2]     = vd0;
                    ald[(size_t)r * 4 + wc * 2 + 1] = vd1;
                }
            }
        }
    }

    // store H in panel layout (PW = 32)
    #pragma unroll
    for (int n = 0; n < 4; ++n) {
        int c = col0 + wc * 64 + n * 16 + cih;
        int p = c >> 5;
        int cw = c & 31;
        #pragma unroll
        for (int m = 0; m < 4; ++m) {
            int r = row0 + wr * 64 + m * 16 + (lane >> 4) * 4;
            #pragma unroll
            for (int j = 0; j < 4; ++j)
                Hpan[(size_t)p * NP * 32 + (size_t)(r + j) * 32 + cw] =
                    __float2bfloat16(acc[m][n][j]);
        }
    }
}

// ---------------------------------------------------------------- XCD-sharded attn, 8-lane group per dst
// HC=256: grid (8, ceil(NN/32)). slice s -> XCD s (grid.x=8, x fastest).
// Wave = 8 groups x 8 lanes; group owns one dst, lane owns 4 cols of the 32-col
// slice. No cross-lane reduction (den accumulated per lane). 2x edge unroll.
__global__ __launch_bounds__(256) void attn256s_kernel(const __hip_bfloat16* __restrict__ Hpan,
                                                       const int* __restrict__ off,
                                                       const int* __restrict__ ssrc,
                                                       const float* __restrict__ als,
                                                       const float* __restrict__ ald,
                                                       const float* __restrict__ bias,
                                                       __hip_bfloat16* __restrict__ Out) {
    int s    = blockIdx.x;
    int head = s >> 1;                   // 32-col slice inside one head (C=64)
    int lane = threadIdx.x & 63;
    int wid  = threadIdx.x >> 6;
    int g    = lane >> 3;
    int q    = lane & 7;
    int d    = blockIdx.y * 32 + wid * 8 + g;
    if (d >= NN) return;

    const __hip_bfloat16* Hp = Hpan + (size_t)s * NP * 32 + q * 4;
    int e0 = off[d], e1 = off[d + 1];
    float aldh = ald[(size_t)d * 4 + head];

    float a0 = 0.f, a1 = 0.f, a2 = 0.f, a3 = 0.f;
    float c0 = 0.f, c1 = 0.f, c2 = 0.f, c3 = 0.f;
    float den0 = 0.f, den1 = 0.f;

    int j = e0;
    for (; j + 1 < e1; j += 2) {
        int s0 = __builtin_nontemporal_load(ssrc + j);
        int s1 = __builtin_nontemporal_load(ssrc + j + 1);
        float x0 = als[(size_t)s0 * 4 + head] + aldh;
        float x1 = als[(size_t)s1 * 4 + head] + aldh;
        x0 = (x0 > 0.f) ? x0 : SLOPE * x0;
        x1 = (x1 > 0.f) ? x1 : SLOPE * x1;
        float w0 = __expf(x0), w1 = __expf(x1);
        den0 += w0; den1 += w1;
        ushort4 v0 = *reinterpret_cast<const ushort4*>(Hp + (size_t)s0 * 32);
        ushort4 v1 = *reinterpret_cast<const ushort4*>(Hp + (size_t)s1 * 32);
        a0 += w0 * bf2f(v0.x); a1 += w0 * bf2f(v0.y);
        a2 += w0 * bf2f(v0.z); a3 += w0 * bf2f(v0.w);
        c0 += w1 * bf2f(v1.x); c1 += w1 * bf2f(v1.y);
        c2 += w1 * bf2f(v1.z); c3 += w1 * bf2f(v1.w);
    }
    if (j < e1) {
        int s0 = __builtin_nontemporal_load(ssrc + j);
        float x0 = als[(size_t)s0 * 4 + head] + aldh;
        x0 = (x0 > 0.f) ? x0 : SLOPE * x0;
        float w0 = __expf(x0);
        den0 += w0;
        ushort4 v0 = *reinterpret_cast<const ushort4*>(Hp + (size_t)s0 * 32);
        a0 += w0 * bf2f(v0.x); a1 += w0 * bf2f(v0.y);
        a2 += w0 * bf2f(v0.z); a3 += w0 * bf2f(v0.w);
    }

    float inv = 1.f / (den0 + den1 + 1e-16f);
    float4 b4 = *reinterpret_cast<const float4*>(bias + s * 32 + q * 4);
    alignas(8) __hip_bfloat16 ob[4];
    ob[0] = __float2bfloat16(fmaxf((a0 + c0) * inv + b4.x, 0.f));
    ob[1] = __float2bfloat16(fmaxf((a1 + c1) * inv + b4.y, 0.f));
    ob[2] = __float2bfloat16(fmaxf((a2 + c2) * inv + b4.z, 0.f));
    ob[3] = __float2bfloat16(fmaxf((a3 + c3) * inv + b4.w, 0.f));
    unsigned long long pk = *reinterpret_cast<unsigned long long*>(ob);
    __builtin_nontemporal_store(pk,
        reinterpret_cast<unsigned long long*>(Out + (size_t)d * 256 + s * 32 + q * 4));
}

// HC=128 final layer, f32 out: 4 slices x 32 cols; slice s == head s (C=32).
__global__ __launch_bounds__(256) void attn128s_kernel(const __hip_bfloat16* __restrict__ Hpan,
                                                       const int* __restrict__ off,
                                                       const int* __restrict__ ssrc,
                                                       const float* __restrict__ als,
                                                       const float* __restrict__ ald,
                                                       const float* __restrict__ bias,
                                                       float* __restrict__ Out) {
    int s    = blockIdx.x;
    int head = s;
    int lane = threadIdx.x & 63;
    int wid  = threadIdx.x >> 6;
    int g    = lane >> 3;
    int q    = lane & 7;
    int d    = blockIdx.y * 32 + wid * 8 + g;
    if (d >= NN) return;

    const __hip_bfloat16* Hp = Hpan + (size_t)s * NP * 32 + q * 4;
    int e0 = off[d], e1 = off[d + 1];
    float aldh = ald[(size_t)d * 4 + head];

    float a0 = 0.f, a1 = 0.f, a2 = 0.f, a3 = 0.f;
    float c0 = 0.f, c1 = 0.f, c2 = 0.f, c3 = 0.f;
    float den0 = 0.f, den1 = 0.f;

    int j = e0;
    for (; j + 1 < e1; j += 2) {
        int s0 = __builtin_nontemporal_load(ssrc + j);
        int s1 = __builtin_nontemporal_load(ssrc + j + 1);
        float x0 = als[(size_t)s0 * 4 + head] + aldh;
        float x1 = als[(size_t)s1 * 4 + head] + aldh;
        x0 = (x0 > 0.f) ? x0 : SLOPE * x0;
        x1 = (x1 > 0.f) ? x1 : SLOPE * x1;
        float w0 = __expf(x0), w1 = __expf(x1);
        den0 += w0; den1 += w1;
        ushort4 v0 = *reinterpret_cast<const ushort4*>(Hp + (size_t)s0 * 32);
        ushort4 v1 = *reinterpret_cast<const ushort4*>(Hp + (size_t)s1 * 32);
        a0 += w0 * bf2f(v0.x); a1 += w0 * bf2f(v0.y);
        a2 += w0 * bf2f(v0.z); a3 += w0 * bf2f(v0.w);
        c0 += w1 * bf2f(v1.x); c1 += w1 * bf2f(v1.y);
        c2 += w1 * bf2f(v1.z); c3 += w1 * bf2f(v1.w);
    }
    if (j < e1) {
        int s0 = __builtin_nontemporal_load(ssrc + j);
        float x0 = als[(size_t)s0 * 4 + head] + aldh;
        x0 = (x0 > 0.f) ? x0 : SLOPE * x0;
        float w0 = __expf(x0);
        den0 += w0;
        ushort4 v0 = *reinterpret_cast<const ushort4*>(Hp + (size_t)s0 * 32);
        a0 += w0 * bf2f(v0.x); a1 += w0 * bf2f(v0.y);
        a2 += w0 * bf2f(v0.z); a3 += w0 * bf2f(v0.w);
    }

    float inv = 1.f / (den0 + den1 + 1e-16f);
    float4 b4 = *reinterpret_cast<const float4*>(bias + s * 32 + q * 4);
    float* op = Out + (size_t)d * 128 + s * 32 + q * 4;
    __builtin_nontemporal_store(fmaxf((a0 + c0) * inv + b4.x, 0.f), op);
    __builtin_nontemporal_store(fmaxf((a1 + c1) * inv + b4.y, 0.f), op + 1);
    __builtin_nontemporal_store(fmaxf((a2 + c2) * inv + b4.z, 0.f), op + 2);
    __builtin_nontemporal_store(fmaxf((a3 + c3) * inv + b4.w, 0.f), op + 3);
}

// ---------------------------------------------------------------- batch norm (bf16 input)
__global__ __launch_bounds__(256) void bnstats_kernel(const __hip_bfloat16* __restrict__ X,
                                                      float* __restrict__ sums) {
    int c  = threadIdx.x;
    int r0 = blockIdx.x * 200;
    float s = 0.f, q = 0.f;
    for (int r = r0; r < r0 + 200; ++r) {
        float v = bf2f(*(const unsigned short*)(X + (size_t)r * 256 + c));
        s += v; q += v * v;
    }
    atomicAdd(&sums[c], s);
    atomicAdd(&sums[256 + c], q);
}

// ---------------------------------------------------------------- launch

extern "C" void kernel_launch(void* const* d_in, const int* in_sizes, int n_in,
                              void* d_out, int out_size, void* d_ws, size_t ws_size,
                              hipStream_t stream) {
    const float* x      = (const float*)d_in[0];
    const int*   ei     = (const int*)d_in[1];
    const float* W1     = (const float*)d_in[2];
    const float* a_s1   = (const float*)d_in[3];
    const float* a_d1   = (const float*)d_in[4];
    const float* b1     = (const float*)d_in[5];
    const float* W2     = (const float*)d_in[6];
    const float* a_s2   = (const float*)d_in[7];
    const float* a_d2   = (const float*)d_in[8];
    const float* b2     = (const float*)d_in[9];
    const float* W3     = (const float*)d_in[10];
    const float* a_s3   = (const float*)d_in[11];
    const float* a_d3   = (const float*)d_in[12];
    const float* b3     = (const float*)d_in[13];
    const float* gamma1 = (const float*)d_in[14];
    const float* beta1  = (const float*)d_in[15];
    const float* gamma2 = (const float*)d_in[16];
    const float* beta2  = (const float*)d_in[17];

    char* ws = (char*)d_ws;
    size_t o = 0;
    auto alloc = [&](size_t bytes) -> void* {
        void* p = ws + o;
        o = (o + bytes + 255) & ~size_t(255);
        return p;
    };
    __hip_bfloat16*  Abf  = (__hip_bfloat16*)alloc((size_t)NP * 256 * 2);
    __hip_bfloat16*  Hbf  = (__hip_bfloat16*)alloc((size_t)NP * 256 * 2);
    __hip_bfloat16*  Xbf  = (__hip_bfloat16*)alloc((size_t)NP * 128 * 2);
    __hip_bfloat16*  WT1  = (__hip_bfloat16*)alloc((size_t)256 * 128 * 2);
    __hip_bfloat16*  WT2  = (__hip_bfloat16*)alloc((size_t)256 * 256 * 2);
    __hip_bfloat16*  WT3  = (__hip_bfloat16*)alloc((size_t)128 * 256 * 2);
    float* bb2   = (float*)alloc(256 * 4);
    float* bb3   = (float*)alloc(128 * 4);
    float* als   = (float*)alloc((size_t)NP * 4 * 4);
    float* ald   = (float*)alloc((size_t)NP * 4 * 4);
    float* sums  = (float*)alloc(512 * 4);
    int*   off   = (int*)alloc((size_t)(NN + 1) * 4);
    int*   cur   = (int*)alloc((size_t)NN * 4);
    int*   cnt   = (int*)alloc((size_t)NN * 4);
    int*   bsum  = (int*)alloc((size_t)NBLK * 4);
    int*   bexc  = (int*)alloc((size_t)NBLK * 4);
    int*   ssrc  = (int*)alloc((size_t)ETOT * 4);
    (void)ws_size; (void)in_sizes; (void)n_in; (void)out_size;

    const int EB = (ETOT + 255) / 256;
    const int DY = (NN + 31) / 32;   // 1563 dst blocks for sharded attn

    // --- CSR build (shared by all 3 layers)
    hipMemsetAsync(cnt, 0, (size_t)NN * 4, stream);
    count_kernel<<<EB, 256, 0, stream>>>(ei, cnt);
    scanA_kernel<<<NBLK, 256, 0, stream>>>(cnt, off, bsum);
    scanB_kernel<<<1, 256, 0, stream>>>(bsum, bexc, off);
    scanC_kernel<<<NBLK, 256, 0, stream>>>(bexc, off, cur);
    fill_kernel<<<EB, 256, 0, stream>>>(ei, cur, ssrc);

    // --- layer 1
    castwx_kernel<<<XB + 128, 256, 0, stream>>>(x, W1, Xbf, WT1);
    mgemm_kernel<128, 256, false><<<dim3(NP / 128, 2), 256, 0, stream>>>(
        Xbf, WT1, nullptr, a_s1, a_d1, Hbf, als, ald);
    attn256s_kernel<<<dim3(8, DY), 256, 0, stream>>>(Hbf, off, ssrc, als, ald, b1, Abf);

    hipMemsetAsync(sums, 0, 512 * 4, stream);
    bnstats_kernel<<<250, 256, 0, stream>>>(Abf, sums);
    foldw_kernel<256><<<256, 256, 0, stream>>>(W2, sums, gamma1, beta1, WT2, bb2);

    // --- layer 2 (BN folded into WT2/bb2)
    mgemm_kernel<256, 256, true><<<dim3(NP / 128, 2), 256, 0, stream>>>(
        Abf, WT2, bb2, a_s2, a_d2, Hbf, als, ald);
    attn256s_kernel<<<dim3(8, DY), 256, 0, stream>>>(Hbf, off, ssrc, als, ald, b2, Abf);

    hipMemsetAsync(sums, 0, 512 * 4, stream);
    bnstats_kernel<<<250, 256, 0, stream>>>(Abf, sums);
    foldw_kernel<128><<<128, 256, 0, stream>>>(W3, sums, gamma2, beta2, WT3, bb3);

    // --- layer 3 (BN folded into WT3/bb3), f32 output
    mgemm_kernel<256, 128, true><<<dim3(NP / 128, 1), 256, 0, stream>>>(
        Abf, WT3, bb3, a_s3, a_d3, Hbf, als, ald);
    attn128s_kernel<<<dim3(4, DY), 256, 0, stream>>>(Hbf, off, ssrc, als, ald, b3, (float*)d_out);
}

// Round 10
// 577.043 us; speedup vs baseline: 1.2071x; 1.0544x over previous
//
#include <hip/hip_runtime.h>
#include <hip/hip_bf16.h>

// Problem constants (fixed by the reference)
constexpr int NN   = 50000;            // nodes
constexpr int EE   = 800000;           // random edges
constexpr int ETOT = EE + NN;          // + self loops
constexpr int NP   = 50048;            // rows padded to multiple of 128 (391*128)
constexpr int NBLK = (NN + 255) / 256; // 196 scan blocks
constexpr float SLOPE  = 0.2f;
constexpr float EPS_BN = 1e-5f;

typedef __attribute__((ext_vector_type(8))) short bf16x8;
typedef __attribute__((ext_vector_type(4))) float f32x4;

__device__ inline float bf2f(unsigned short u) {
    union { unsigned int i; float f; } c; c.i = ((unsigned int)u) << 16; return c.f;
}

__device__ inline void gload16(const __hip_bfloat16* g, __hip_bfloat16* l) {
    __builtin_amdgcn_global_load_lds(
        (const __attribute__((address_space(1))) unsigned int*)g,
        (__attribute__((address_space(3))) unsigned int*)l, 16, 0, 0);
}

// ---------------------------------------------------------------- CSR build

__global__ __launch_bounds__(256) void count_kernel(const int* __restrict__ ei,
                                                    int* __restrict__ cnt) {
    int j = blockIdx.x * 256 + threadIdx.x;
    if (j >= ETOT) return;
    int dst = (j < EE) ? ei[EE + j] : (j - EE);
    atomicAdd(&cnt[dst], 1);
}

__global__ __launch_bounds__(256) void scanA_kernel(const int* __restrict__ cnt,
                                                    int* __restrict__ off,
                                                    int* __restrict__ bsum) {
    int b = blockIdx.x, t = threadIdx.x;
    int i = b * 256 + t;
    int v = (i < NN) ? cnt[i] : 0;
    int lane = t & 63, w = t >> 6;
    int x = v;
    #pragma unroll
    for (int o = 1; o < 64; o <<= 1) { int y = __shfl_up(x, o); if (lane >= o) x += y; }
    __shared__ int ws[4];
    if (lane == 63) ws[w] = x;
    __syncthreads();
    int wo = 0;
    for (int k = 0; k < w; ++k) wo += ws[k];
    int incl = x + wo;
    if (i < NN) off[i] = incl - v;
    if (t == 255) bsum[b] = incl;
}

__global__ __launch_bounds__(256) void scanB_kernel(const int* __restrict__ bsum,
                                                    int* __restrict__ bexc,
                                                    int* __restrict__ off) {
    int t = threadIdx.x;
    int v = (t < NBLK) ? bsum[t] : 0;
    int lane = t & 63, w = t >> 6;
    int x = v;
    #pragma unroll
    for (int o = 1; o < 64; o <<= 1) { int y = __shfl_up(x, o); if (lane >= o) x += y; }
    __shared__ int ws[4];
    if (lane == 63) ws[w] = x;
    __syncthreads();
    int wo = 0;
    for (int k = 0; k < w; ++k) wo += ws[k];
    int incl = x + wo;
    if (t < NBLK) bexc[t] = incl - v;
    if (t == 255) off[NN] = incl;
}

__global__ __launch_bounds__(256) void scanC_kernel(const int* __restrict__ bexc,
                                                    int* __restrict__ off,
                                                    int* __restrict__ cur) {
    int i = blockIdx.x * 256 + threadIdx.x;
    if (i >= NN) return;
    int v = off[i] + bexc[blockIdx.x];
    off[i] = v;
    cur[i] = v;
}

__global__ __launch_bounds__(256) void fill_kernel(const int* __restrict__ ei,
                                                   int* __restrict__ cursor,
                                                   int* __restrict__ ssrc) {
    int j = blockIdx.x * 256 + threadIdx.x;
    if (j >= ETOT) return;
    int src, dst;
    if (j < EE) { src = ei[j]; dst = ei[EE + j]; }
    else        { src = dst = j - EE; }
    int pos = atomicAdd(&cursor[dst], 1);
    ssrc[pos] = src;
}

// ---------------------------------------------------------------- layer-1 casts (fused)
constexpr int XB = (int)(((long)NP * 128 / 8 + 255) / 256);
__global__ __launch_bounds__(256) void castwx_kernel(const float* __restrict__ X,
                                                     const float* __restrict__ W,
                                                     __hip_bfloat16* __restrict__ Xbf,
                                                     __hip_bfloat16* __restrict__ WT) {
    int b = blockIdx.x;
    if (b < XB) {
        long e0 = ((long)b * 256 + threadIdx.x) * 8;
        if (e0 >= (long)NP * 128) return;
        int row = (int)(e0 / 128);
        __hip_bfloat16 o[8];
        if (row < NN) {
            float4 v0 = *reinterpret_cast<const float4*>(X + e0);
            float4 v1 = *reinterpret_cast<const float4*>(X + e0 + 4);
            o[0] = __float2bfloat16(v0.x); o[1] = __float2bfloat16(v0.y);
            o[2] = __float2bfloat16(v0.z); o[3] = __float2bfloat16(v0.w);
            o[4] = __float2bfloat16(v1.x); o[5] = __float2bfloat16(v1.y);
            o[6] = __float2bfloat16(v1.z); o[7] = __float2bfloat16(v1.w);
        } else {
            for (int j = 0; j < 8; ++j) o[j] = __float2bfloat16(0.f);
        }
        *reinterpret_cast<bf16x8*>(Xbf + e0) = *reinterpret_cast<bf16x8*>(o);
    } else {
        int i = (b - XB) * 256 + threadIdx.x;
        int c = i / 128, k = i % 128;
        WT[i] = __float2bfloat16(W[(size_t)k * 256 + c]);
    }
}

// fold BN (from raw sums) + transpose next-layer W
template <int WOUT>
__global__ __launch_bounds__(256) void foldw_kernel(const float* __restrict__ W,
                                                    const float* __restrict__ sums,
                                                    const float* __restrict__ gamma,
                                                    const float* __restrict__ beta,
                                                    __hip_bfloat16* __restrict__ WTp,
                                                    float* __restrict__ bb) {
    int c = blockIdx.x, k = threadIdx.x;
    float mean = sums[k] / (float)NN;
    float var  = sums[256 + k] / (float)NN - mean * mean;
    float inv  = rsqrtf(var + EPS_BN);
    float sc   = gamma[k] * inv;
    float sh   = beta[k] - mean * sc;
    float w = W[(size_t)k * WOUT + c];
    WTp[(size_t)c * 256 + k] = __float2bfloat16(sc * w);
    float p = sh * w;
    #pragma unroll
    for (int o = 1; o < 64; o <<= 1) p += __shfl_xor(p, o);
    __shared__ float ps[4];
    if ((k & 63) == 0) ps[k >> 6] = p;
    __syncthreads();
    if (k == 0) bb[c] = ps[0] + ps[1] + ps[2] + ps[3];
}

// ---------------------------------------------------------------- MFMA GEMM + fused al_src/al_dst
// H written in 16-col PANEL layout: panel p = cols [p*16,(p+1)*16) over all rows.
// Panel = NP*16*2B = 1.6 MB -> proven L2-resident width (R8 FETCH evidence).
template <int FIN, int WOUT, bool FOLD>
__global__ __launch_bounds__(256) void mgemm_kernel(const __hip_bfloat16* __restrict__ A,
                                                    const __hip_bfloat16* __restrict__ BT,
                                                    const float* __restrict__ bb,
                                                    const float* __restrict__ a_src,
                                                    const float* __restrict__ a_dst,
                                                    __hip_bfloat16* __restrict__ Hpan,
                                                    float* __restrict__ als,
                                                    float* __restrict__ ald) {
    __shared__ __hip_bfloat16 As[128 * 32];
    __shared__ __hip_bfloat16 Bs[128 * 32];
    int t = threadIdx.x;
    int lane = t & 63, w = t >> 6;
    int row0 = blockIdx.x * 128;
    int col0 = blockIdx.y * 128;
    int wr = w >> 1, wc = w & 1;

    f32x4 acc[4][4];
    #pragma unroll
    for (int m = 0; m < 4; ++m)
        #pragma unroll
        for (int n = 0; n < 4; ++n) acc[m][n] = (f32x4){0.f, 0.f, 0.f, 0.f};

    int srow = w * 32 + (lane >> 2);
    int sbc  = (lane & 3) * 8;
    const __hip_bfloat16* gA0 = A  + (size_t)(row0 + srow)      * FIN + sbc;
    const __hip_bfloat16* gA1 = A  + (size_t)(row0 + srow + 16) * FIN + sbc;
    const __hip_bfloat16* gB0 = BT + (size_t)(col0 + srow)      * FIN + sbc;
    const __hip_bfloat16* gB1 = BT + (size_t)(col0 + srow + 16) * FIN + sbc;
    __hip_bfloat16* lA0 = As + w * 1024;
    __hip_bfloat16* lA1 = As + w * 1024 + 512;
    __hip_bfloat16* lB0 = Bs + w * 1024;
    __hip_bfloat16* lB1 = Bs + w * 1024 + 512;

    int rA = (wr * 64 + (lane & 15)) * 32 + (lane >> 4) * 8;
    int rB = (wc * 64 + (lane & 15)) * 32 + (lane >> 4) * 8;

    for (int k0 = 0; k0 < FIN; k0 += 32) {
        gload16(gA0 + k0, lA0);
        gload16(gA1 + k0, lA1);
        gload16(gB0 + k0, lB0);
        gload16(gB1 + k0, lB1);
        __syncthreads();
        bf16x8 af[4], bfr[4];
        #pragma unroll
        for (int m = 0; m < 4; ++m) af[m]  = *reinterpret_cast<const bf16x8*>(As + rA + m * 16 * 32);
        #pragma unroll
        for (int n = 0; n < 4; ++n) bfr[n] = *reinterpret_cast<const bf16x8*>(Bs + rB + n * 16 * 32);
        #pragma unroll
        for (int m = 0; m < 4; ++m)
            #pragma unroll
            for (int n = 0; n < 4; ++n)
                acc[m][n] = __builtin_amdgcn_mfma_f32_16x16x32_bf16(af[m], bfr[n], acc[m][n], 0, 0, 0);
        __syncthreads();
    }

    int cih = lane & 15;

    if constexpr (FOLD) {
        #pragma unroll
        for (int n = 0; n < 4; ++n) {
            float badd = bb[col0 + wc * 64 + n * 16 + cih];
            #pragma unroll
            for (int m = 0; m < 4; ++m)
                #pragma unroll
                for (int j = 0; j < 4; ++j) acc[m][n][j] += badd;
        }
    }

    float asv[4], adv[4];
    int headw = 0;
    if constexpr (WOUT == 256) {
        headw = (col0 >> 6) + wc;
        #pragma unroll
        for (int n = 0; n < 4; ++n) {
            asv[n] = a_src[headw * 64 + n * 16 + cih];
            adv[n] = a_dst[headw * 64 + n * 16 + cih];
        }
    } else {
        #pragma unroll
        for (int n = 0; n < 4; ++n) {
            int hh = wc * 2 + (n >> 1);
            asv[n] = a_src[hh * 32 + (n & 1) * 16 + cih];
            adv[n] = a_dst[hh * 32 + (n & 1) * 16 + cih];
        }
    }

    #pragma unroll
    for (int m = 0; m < 4; ++m) {
        #pragma unroll
        for (int j = 0; j < 4; ++j) {
            int r = row0 + wr * 64 + m * 16 + (lane >> 4) * 4 + j;
            if constexpr (WOUT == 256) {
                float vs = acc[m][0][j] * asv[0] + acc[m][1][j] * asv[1]
                         + acc[m][2][j] * asv[2] + acc[m][3][j] * asv[3];
                float vd = acc[m][0][j] * adv[0] + acc[m][1][j] * adv[1]
                         + acc[m][2][j] * adv[2] + acc[m][3][j] * adv[3];
                #pragma unroll
                for (int o = 1; o < 16; o <<= 1) {
                    vs += __shfl_xor(vs, o);
                    vd += __shfl_xor(vd, o);
                }
                if (cih == 0) {
                    als[(size_t)r * 4 + headw] = vs;
                    ald[(size_t)r * 4 + headw] = vd;
                }
            } else {
                float vs0 = acc[m][0][j] * asv[0] + acc[m][1][j] * asv[1];
                float vs1 = acc[m][2][j] * asv[2] + acc[m][3][j] * asv[3];
                float vd0 = acc[m][0][j] * adv[0] + acc[m][1][j] * adv[1];
                float vd1 = acc[m][2][j] * adv[2] + acc[m][3][j] * adv[3];
                #pragma unroll
                for (int o = 1; o < 16; o <<= 1) {
                    vs0 += __shfl_xor(vs0, o); vs1 += __shfl_xor(vs1, o);
                    vd0 += __shfl_xor(vd0, o); vd1 += __shfl_xor(vd1, o);
                }
                if (cih == 0) {
                    als[(size_t)r * 4 + wc * 2]     = vs0;
                    als[(size_t)r * 4 + wc * 2 + 1] = vs1;
                    ald[(size_t)r * 4 + wc * 2]     = vd0;
                    ald[(size_t)r * 4 + wc * 2 + 1] = vd1;
                }
            }
        }
    }

    // store H in 16-col panel layout
    #pragma unroll
    for (int n = 0; n < 4; ++n) {
        int c = col0 + wc * 64 + n * 16 + cih;
        int p = c >> 4;
        int cw = c & 15;
        #pragma unroll
        for (int m = 0; m < 4; ++m) {
            int r = row0 + wr * 64 + m * 16 + (lane >> 4) * 4;
            #pragma unroll
            for (int j = 0; j < 4; ++j)
                Hpan[(size_t)p * NP * 16 + (size_t)(r + j) * 16 + cw] =
                    __float2bfloat16(acc[m][n][j]);
        }
    }
}

// ---------------------------------------------------------------- XCD-sharded attn, cluster-per-dst
// grid (8, ceil(NN/64)); slice s = blockIdx.x + sbase -> XCD blockIdx.x.
// Wave = 16 clusters x 4 lanes. Cluster owns one dst; lane owns 4 cols of the
// 16-col slice (one 8B load per edge). No cross-lane reduction anywhere.
template <int HC, bool OUTBF>
__global__ __launch_bounds__(256) void attns_kernel(const __hip_bfloat16* __restrict__ Hpan,
                                                    const int* __restrict__ off,
                                                    const int* __restrict__ ssrc,
                                                    const float* __restrict__ als,
                                                    const float* __restrict__ ald,
                                                    const float* __restrict__ bias,
                                                    void* __restrict__ Outv,
                                                    int sbase) {
    int s    = blockIdx.x + sbase;
    int head = (HC == 256) ? (s >> 2) : (s >> 1);
    int lane = threadIdx.x & 63;
    int wid  = threadIdx.x >> 6;
    int cl   = lane >> 2;                // cluster (dst) 0..15
    int q    = lane & 3;                 // 4-col segment of the slice
    int d    = blockIdx.y * 64 + wid * 16 + cl;
    if (d >= NN) return;

    const __hip_bfloat16* Hp = Hpan + (size_t)s * NP * 16 + q * 4;
    int e0 = off[d], e1 = off[d + 1];
    float aldh = ald[(size_t)d * 4 + head];

    float a0 = 0.f, a1 = 0.f, a2 = 0.f, a3 = 0.f;
    float c0 = 0.f, c1 = 0.f, c2 = 0.f, c3 = 0.f;
    float den0 = 0.f, den1 = 0.f;

    int j = e0;
    for (; j + 1 < e1; j += 2) {
        int s0 = ssrc[j];
        int s1 = ssrc[j + 1];
        float x0 = als[(size_t)s0 * 4 + head] + aldh;
        float x1 = als[(size_t)s1 * 4 + head] + aldh;
        x0 = (x0 > 0.f) ? x0 : SLOPE * x0;
        x1 = (x1 > 0.f) ? x1 : SLOPE * x1;
        float w0 = __expf(x0), w1 = __expf(x1);
        den0 += w0; den1 += w1;
        ushort4 v0 = *reinterpret_cast<const ushort4*>(Hp + (size_t)s0 * 16);
        ushort4 v1 = *reinterpret_cast<const ushort4*>(Hp + (size_t)s1 * 16);
        a0 += w0 * bf2f(v0.x); a1 += w0 * bf2f(v0.y);
        a2 += w0 * bf2f(v0.z); a3 += w0 * bf2f(v0.w);
        c0 += w1 * bf2f(v1.x); c1 += w1 * bf2f(v1.y);
        c2 += w1 * bf2f(v1.z); c3 += w1 * bf2f(v1.w);
    }
    if (j < e1) {
        int s0 = ssrc[j];
        float x0 = als[(size_t)s0 * 4 + head] + aldh;
        x0 = (x0 > 0.f) ? x0 : SLOPE * x0;
        float w0 = __expf(x0);
        den0 += w0;
        ushort4 v0 = *reinterpret_cast<const ushort4*>(Hp + (size_t)s0 * 16);
        a0 += w0 * bf2f(v0.x); a1 += w0 * bf2f(v0.y);
        a2 += w0 * bf2f(v0.z); a3 += w0 * bf2f(v0.w);
    }

    float inv = 1.f / (den0 + den1 + 1e-16f);
    float4 b4 = *reinterpret_cast<const float4*>(bias + s * 16 + q * 4);
    float o0 = fmaxf((a0 + c0) * inv + b4.x, 0.f);
    float o1 = fmaxf((a1 + c1) * inv + b4.y, 0.f);
    float o2 = fmaxf((a2 + c2) * inv + b4.z, 0.f);
    float o3 = fmaxf((a3 + c3) * inv + b4.w, 0.f);

    if constexpr (OUTBF) {
        alignas(8) __hip_bfloat16 ob[4];
        ob[0] = __float2bfloat16(o0); ob[1] = __float2bfloat16(o1);
        ob[2] = __float2bfloat16(o2); ob[3] = __float2bfloat16(o3);
        *reinterpret_cast<unsigned long long*>(
            (__hip_bfloat16*)Outv + (size_t)d * HC + s * 16 + q * 4) =
            *reinterpret_cast<unsigned long long*>(ob);
    } else {
        *reinterpret_cast<float4*>((float*)Outv + (size_t)d * HC + s * 16 + q * 4) =
            make_float4(o0, o1, o2, o3);
    }
}

// ---------------------------------------------------------------- batch norm (bf16 input)
__global__ __launch_bounds__(256) void bnstats_kernel(const __hip_bfloat16* __restrict__ X,
                                                      float* __restrict__ sums) {
    int c  = threadIdx.x;
    int r0 = blockIdx.x * 200;
    float s = 0.f, q = 0.f;
    for (int r = r0; r < r0 + 200; ++r) {
        float v = bf2f(*(const unsigned short*)(X + (size_t)r * 256 + c));
        s += v; q += v * v;
    }
    atomicAdd(&sums[c], s);
    atomicAdd(&sums[256 + c], q);
}

// ---------------------------------------------------------------- launch

extern "C" void kernel_launch(void* const* d_in, const int* in_sizes, int n_in,
                              void* d_out, int out_size, void* d_ws, size_t ws_size,
                              hipStream_t stream) {
    const float* x      = (const float*)d_in[0];
    const int*   ei     = (const int*)d_in[1];
    const float* W1     = (const float*)d_in[2];
    const float* a_s1   = (const float*)d_in[3];
    const float* a_d1   = (const float*)d_in[4];
    const float* b1     = (const float*)d_in[5];
    const float* W2     = (const float*)d_in[6];
    const float* a_s2   = (const float*)d_in[7];
    const float* a_d2   = (const float*)d_in[8];
    const float* b2     = (const float*)d_in[9];
    const float* W3     = (const float*)d_in[10];
    const float* a_s3   = (const float*)d_in[11];
    const float* a_d3   = (const float*)d_in[12];
    const float* b3     = (const float*)d_in[13];
    const float* gamma1 = (const float*)d_in[14];
    const float* beta1  = (const float*)d_in[15];
    const float* gamma2 = (const float*)d_in[16];
    const float* beta2  = (const float*)d_in[17];

    char* ws = (char*)d_ws;
    size_t o = 0;
    auto alloc = [&](size_t bytes) -> void* {
        void* p = ws + o;
        o = (o + bytes + 255) & ~size_t(255);
        return p;
    };
    __hip_bfloat16*  Abf  = (__hip_bfloat16*)alloc((size_t)NP * 256 * 2);
    __hip_bfloat16*  Hbf  = (__hip_bfloat16*)alloc((size_t)NP * 256 * 2);
    __hip_bfloat16*  Xbf  = (__hip_bfloat16*)alloc((size_t)NP * 128 * 2);
    __hip_bfloat16*  WT1  = (__hip_bfloat16*)alloc((size_t)256 * 128 * 2);
    __hip_bfloat16*  WT2  = (__hip_bfloat16*)alloc((size_t)256 * 256 * 2);
    __hip_bfloat16*  WT3  = (__hip_bfloat16*)alloc((size_t)128 * 256 * 2);
    float* bb2   = (float*)alloc(256 * 4);
    float* bb3   = (float*)alloc(128 * 4);
    float* als   = (float*)alloc((size_t)NP * 4 * 4);
    float* ald   = (float*)alloc((size_t)NP * 4 * 4);
    float* sums  = (float*)alloc(512 * 4);
    int*   off   = (int*)alloc((size_t)(NN + 1) * 4);
    int*   cur   = (int*)alloc((size_t)NN * 4);
    int*   cnt   = (int*)alloc((size_t)NN * 4);
    int*   bsum  = (int*)alloc((size_t)NBLK * 4);
    int*   bexc  = (int*)alloc((size_t)NBLK * 4);
    int*   ssrc  = (int*)alloc((size_t)ETOT * 4);
    (void)ws_size; (void)in_sizes; (void)n_in; (void)out_size;

    const int EB = (ETOT + 255) / 256;
    const int DY = (NN + 63) / 64;   // 782 dst blocks per slice-launch

    // --- CSR build (shared by all 3 layers)
    hipMemsetAsync(cnt, 0, (size_t)NN * 4, stream);
    count_kernel<<<EB, 256, 0, stream>>>(ei, cnt);
    scanA_kernel<<<NBLK, 256, 0, stream>>>(cnt, off, bsum);
    scanB_kernel<<<1, 256, 0, stream>>>(bsum, bexc, off);
    scanC_kernel<<<NBLK, 256, 0, stream>>>(bexc, off, cur);
    fill_kernel<<<EB, 256, 0, stream>>>(ei, cur, ssrc);

    // --- layer 1
    castwx_kernel<<<XB + 128, 256, 0, stream>>>(x, W1, Xbf, WT1);
    mgemm_kernel<128, 256, false><<<dim3(NP / 128, 2), 256, 0, stream>>>(
        Xbf, WT1, nullptr, a_s1, a_d1, Hbf, als, ald);
    attns_kernel<256, true><<<dim3(8, DY), 256, 0, stream>>>(Hbf, off, ssrc, als, ald, b1, Abf, 0);
    attns_kernel<256, true><<<dim3(8, DY), 256, 0, stream>>>(Hbf, off, ssrc, als, ald, b1, Abf, 8);

    hipMemsetAsync(sums, 0, 512 * 4, stream);
    bnstats_kernel<<<250, 256, 0, stream>>>(Abf, sums);
    foldw_kernel<256><<<256, 256, 0, stream>>>(W2, sums, gamma1, beta1, WT2, bb2);

    // --- layer 2 (BN folded into WT2/bb2)
    mgemm_kernel<256, 256, true><<<dim3(NP / 128, 2), 256, 0, stream>>>(
        Abf, WT2, bb2, a_s2, a_d2, Hbf, als, ald);
    attns_kernel<256, true><<<dim3(8, DY), 256, 0, stream>>>(Hbf, off, ssrc, als, ald, b2, Abf, 0);
    attns_kernel<256, true><<<dim3(8, DY), 256, 0, stream>>>(Hbf, off, ssrc, als, ald, b2, Abf, 8);

    hipMemsetAsync(sums, 0, 512 * 4, stream);
    bnstats_kernel<<<250, 256, 0, stream>>>(Abf, sums);
    foldw_kernel<128><<<128, 256, 0, stream>>>(W3, sums, gamma2, beta2, WT3, bb3);

    // --- layer 3 (BN folded into WT3/bb3), f32 output
    mgemm_kernel<256, 128, true><<<dim3(NP / 128, 1), 256, 0, stream>>>(
        Abf, WT3, bb3, a_s3, a_d3, Hbf, als, ald);
    attns_kernel<128, false><<<dim3(8, DY), 256, 0, stream>>>(Hbf, off, ssrc, als, ald, b3, d_out, 0);
}

// Round 11
// 378.064 us; speedup vs baseline: 1.8424x; 1.5263x over previous
//
#include <hip/hip_runtime.h>
#include <hip/hip_bf16.h>

// Problem constants (fixed by the reference)
constexpr int NN   = 50000;            // nodes
constexpr int EE   = 800000;           // random edges
constexpr int ETOT = EE + NN;          // + self loops
constexpr int NP   = 50048;            // rows padded to multiple of 128 (391*128)
constexpr int NBLK = (NN + 255) / 256; // 196 scan blocks
constexpr float SLOPE  = 0.2f;
constexpr float EPS_BN = 1e-5f;

typedef __attribute__((ext_vector_type(8))) short bf16x8;
typedef __attribute__((ext_vector_type(4))) float f32x4;

__device__ inline float bf2f(unsigned short u) {
    union { unsigned int i; float f; } c; c.i = ((unsigned int)u) << 16; return c.f;
}

__device__ inline void gload16(const __hip_bfloat16* g, __hip_bfloat16* l) {
    __builtin_amdgcn_global_load_lds(
        (const __attribute__((address_space(1))) unsigned int*)g,
        (__attribute__((address_space(3))) unsigned int*)l, 16, 0, 0);
}

// ---------------------------------------------------------------- CSR build

__global__ __launch_bounds__(256) void count_kernel(const int* __restrict__ ei,
                                                    int* __restrict__ cnt) {
    int j = blockIdx.x * 256 + threadIdx.x;
    if (j >= ETOT) return;
    int dst = (j < EE) ? ei[EE + j] : (j - EE);
    atomicAdd(&cnt[dst], 1);
}

__global__ __launch_bounds__(256) void scanA_kernel(const int* __restrict__ cnt,
                                                    int* __restrict__ off,
                                                    int* __restrict__ bsum) {
    int b = blockIdx.x, t = threadIdx.x;
    int i = b * 256 + t;
    int v = (i < NN) ? cnt[i] : 0;
    int lane = t & 63, w = t >> 6;
    int x = v;
    #pragma unroll
    for (int o = 1; o < 64; o <<= 1) { int y = __shfl_up(x, o); if (lane >= o) x += y; }
    __shared__ int ws[4];
    if (lane == 63) ws[w] = x;
    __syncthreads();
    int wo = 0;
    for (int k = 0; k < w; ++k) wo += ws[k];
    int incl = x + wo;
    if (i < NN) off[i] = incl - v;
    if (t == 255) bsum[b] = incl;
}

__global__ __launch_bounds__(256) void scanB_kernel(const int* __restrict__ bsum,
                                                    int* __restrict__ bexc,
                                                    int* __restrict__ off) {
    int t = threadIdx.x;
    int v = (t < NBLK) ? bsum[t] : 0;
    int lane = t & 63, w = t >> 6;
    int x = v;
    #pragma unroll
    for (int o = 1; o < 64; o <<= 1) { int y = __shfl_up(x, o); if (lane >= o) x += y; }
    __shared__ int ws[4];
    if (lane == 63) ws[w] = x;
    __syncthreads();
    int wo = 0;
    for (int k = 0; k < w; ++k) wo += ws[k];
    int incl = x + wo;
    if (t < NBLK) bexc[t] = incl - v;
    if (t == 255) off[NN] = incl;
}

__global__ __launch_bounds__(256) void scanC_kernel(const int* __restrict__ bexc,
                                                    int* __restrict__ off,
                                                    int* __restrict__ cur) {
    int i = blockIdx.x * 256 + threadIdx.x;
    if (i >= NN) return;
    int v = off[i] + bexc[blockIdx.x];
    off[i] = v;
    cur[i] = v;
}

__global__ __launch_bounds__(256) void fill_kernel(const int* __restrict__ ei,
                                                   int* __restrict__ cursor,
                                                   int* __restrict__ ssrc) {
    int j = blockIdx.x * 256 + threadIdx.x;
    if (j >= ETOT) return;
    int src, dst;
    if (j < EE) { src = ei[j]; dst = ei[EE + j]; }
    else        { src = dst = j - EE; }
    int pos = atomicAdd(&cursor[dst], 1);
    ssrc[pos] = src;
}

// ---------------------------------------------------------------- layer-1 casts (fused)
constexpr int XB = (int)(((long)NP * 128 / 8 + 255) / 256);
__global__ __launch_bounds__(256) void castwx_kernel(const float* __restrict__ X,
                                                     const float* __restrict__ W,
                                                     __hip_bfloat16* __restrict__ Xbf,
                                                     __hip_bfloat16* __restrict__ WT) {
    int b = blockIdx.x;
    if (b < XB) {
        long e0 = ((long)b * 256 + threadIdx.x) * 8;
        if (e0 >= (long)NP * 128) return;
        int row = (int)(e0 / 128);
        __hip_bfloat16 o[8];
        if (row < NN) {
            float4 v0 = *reinterpret_cast<const float4*>(X + e0);
            float4 v1 = *reinterpret_cast<const float4*>(X + e0 + 4);
            o[0] = __float2bfloat16(v0.x); o[1] = __float2bfloat16(v0.y);
            o[2] = __float2bfloat16(v0.z); o[3] = __float2bfloat16(v0.w);
            o[4] = __float2bfloat16(v1.x); o[5] = __float2bfloat16(v1.y);
            o[6] = __float2bfloat16(v1.z); o[7] = __float2bfloat16(v1.w);
        } else {
            for (int j = 0; j < 8; ++j) o[j] = __float2bfloat16(0.f);
        }
        *reinterpret_cast<bf16x8*>(Xbf + e0) = *reinterpret_cast<bf16x8*>(o);
    } else {
        int i = (b - XB) * 256 + threadIdx.x;
        int c = i / 128, k = i % 128;
        WT[i] = __float2bfloat16(W[(size_t)k * 256 + c]);
    }
}

// fold BN (from raw sums) + transpose next-layer W; bb[c] = sum_k shift[k]*W[k][c]
template <int WOUT>
__global__ __launch_bounds__(256) void foldw_kernel(const float* __restrict__ W,
                                                    const float* __restrict__ sums,
                                                    const float* __restrict__ gamma,
                                                    const float* __restrict__ beta,
                                                    __hip_bfloat16* __restrict__ WTp,
                                                    float* __restrict__ bb) {
    int c = blockIdx.x, k = threadIdx.x;
    float mean = sums[k] / (float)NN;
    float var  = sums[256 + k] / (float)NN - mean * mean;
    float inv  = rsqrtf(var + EPS_BN);
    float sc   = gamma[k] * inv;
    float sh   = beta[k] - mean * sc;
    float w = W[(size_t)k * WOUT + c];
    WTp[(size_t)c * 256 + k] = __float2bfloat16(sc * w);
    float p = sh * w;
    #pragma unroll
    for (int o = 1; o < 64; o <<= 1) p += __shfl_xor(p, o);
    __shared__ float ps[4];
    if ((k & 63) == 0) ps[k >> 6] = p;
    __syncthreads();
    if (k == 0) bb[c] = ps[0] + ps[1] + ps[2] + ps[3];
}

// ---------------------------------------------------------------- MFMA GEMM + fused al_src/al_dst
template <int FIN, int WOUT, bool FOLD>
__global__ __launch_bounds__(256) void mgemm_kernel(const __hip_bfloat16* __restrict__ A,
                                                    const __hip_bfloat16* __restrict__ BT,
                                                    const float* __restrict__ bb,
                                                    const float* __restrict__ a_src,
                                                    const float* __restrict__ a_dst,
                                                    __hip_bfloat16* __restrict__ Hbf,
                                                    float* __restrict__ als,
                                                    float* __restrict__ ald) {
    __shared__ __hip_bfloat16 As[128 * 32];
    __shared__ __hip_bfloat16 Bs[128 * 32];
    int t = threadIdx.x;
    int lane = t & 63, w = t >> 6;
    int row0 = blockIdx.x * 128;
    int col0 = blockIdx.y * 128;
    int wr = w >> 1, wc = w & 1;

    f32x4 acc[4][4];
    #pragma unroll
    for (int m = 0; m < 4; ++m)
        #pragma unroll
        for (int n = 0; n < 4; ++n) acc[m][n] = (f32x4){0.f, 0.f, 0.f, 0.f};

    int srow = w * 32 + (lane >> 2);
    int sbc  = (lane & 3) * 8;
    const __hip_bfloat16* gA0 = A  + (size_t)(row0 + srow)      * FIN + sbc;
    const __hip_bfloat16* gA1 = A  + (size_t)(row0 + srow + 16) * FIN + sbc;
    const __hip_bfloat16* gB0 = BT + (size_t)(col0 + srow)      * FIN + sbc;
    const __hip_bfloat16* gB1 = BT + (size_t)(col0 + srow + 16) * FIN + sbc;
    __hip_bfloat16* lA0 = As + w * 1024;
    __hip_bfloat16* lA1 = As + w * 1024 + 512;
    __hip_bfloat16* lB0 = Bs + w * 1024;
    __hip_bfloat16* lB1 = Bs + w * 1024 + 512;

    int rA = (wr * 64 + (lane & 15)) * 32 + (lane >> 4) * 8;
    int rB = (wc * 64 + (lane & 15)) * 32 + (lane >> 4) * 8;

    for (int k0 = 0; k0 < FIN; k0 += 32) {
        gload16(gA0 + k0, lA0);
        gload16(gA1 + k0, lA1);
        gload16(gB0 + k0, lB0);
        gload16(gB1 + k0, lB1);
        __syncthreads();
        bf16x8 af[4], bfr[4];
        #pragma unroll
        for (int m = 0; m < 4; ++m) af[m]  = *reinterpret_cast<const bf16x8*>(As + rA + m * 16 * 32);
        #pragma unroll
        for (int n = 0; n < 4; ++n) bfr[n] = *reinterpret_cast<const bf16x8*>(Bs + rB + n * 16 * 32);
        #pragma unroll
        for (int m = 0; m < 4; ++m)
            #pragma unroll
            for (int n = 0; n < 4; ++n)
                acc[m][n] = __builtin_amdgcn_mfma_f32_16x16x32_bf16(af[m], bfr[n], acc[m][n], 0, 0, 0);
        __syncthreads();
    }

    int cih = lane & 15;

    if constexpr (FOLD) {
        #pragma unroll
        for (int n = 0; n < 4; ++n) {
            float badd = bb[col0 + wc * 64 + n * 16 + cih];
            #pragma unroll
            for (int m = 0; m < 4; ++m)
                #pragma unroll
                for (int j = 0; j < 4; ++j) acc[m][n][j] += badd;
        }
    }

    float asv[4], adv[4];
    int headw = 0;
    if constexpr (WOUT == 256) {
        headw = (col0 >> 6) + wc;
        #pragma unroll
        for (int n = 0; n < 4; ++n) {
            asv[n] = a_src[headw * 64 + n * 16 + cih];
            adv[n] = a_dst[headw * 64 + n * 16 + cih];
        }
    } else {
        #pragma unroll
        for (int n = 0; n < 4; ++n) {
            int hh = wc * 2 + (n >> 1);
            asv[n] = a_src[hh * 32 + (n & 1) * 16 + cih];
            adv[n] = a_dst[hh * 32 + (n & 1) * 16 + cih];
        }
    }

    #pragma unroll
    for (int m = 0; m < 4; ++m) {
        #pragma unroll
        for (int j = 0; j < 4; ++j) {
            int r = row0 + wr * 64 + m * 16 + (lane >> 4) * 4 + j;
            if constexpr (WOUT == 256) {
                float vs = acc[m][0][j] * asv[0] + acc[m][1][j] * asv[1]
                         + acc[m][2][j] * asv[2] + acc[m][3][j] * asv[3];
                float vd = acc[m][0][j] * adv[0] + acc[m][1][j] * adv[1]
                         + acc[m][2][j] * adv[2] + acc[m][3][j] * adv[3];
                #pragma unroll
                for (int o = 1; o < 16; o <<= 1) {
                    vs += __shfl_xor(vs, o);
                    vd += __shfl_xor(vd, o);
                }
                if (cih == 0) {
                    als[(size_t)r * 4 + headw] = vs;
                    ald[(size_t)r * 4 + headw] = vd;
                }
            } else {
                float vs0 = acc[m][0][j] * asv[0] + acc[m][1][j] * asv[1];
                float vs1 = acc[m][2][j] * asv[2] + acc[m][3][j] * asv[3];
                float vd0 = acc[m][0][j] * adv[0] + acc[m][1][j] * adv[1];
                float vd1 = acc[m][2][j] * adv[2] + acc[m][3][j] * adv[3];
                #pragma unroll
                for (int o = 1; o < 16; o <<= 1) {
                    vs0 += __shfl_xor(vs0, o); vs1 += __shfl_xor(vs1, o);
                    vd0 += __shfl_xor(vd0, o); vd1 += __shfl_xor(vd1, o);
                }
                if (cih == 0) {
                    als[(size_t)r * 4 + wc * 2]     = vs0;
                    als[(size_t)r * 4 + wc * 2 + 1] = vs1;
                    ald[(size_t)r * 4 + wc * 2]     = vd0;
                    ald[(size_t)r * 4 + wc * 2 + 1] = vd1;
                }
            }
        }
    }

    #pragma unroll
    for (int n = 0; n < 4; ++n) {
        int c = col0 + wc * 64 + n * 16 + cih;
        #pragma unroll
        for (int m = 0; m < 4; ++m) {
            int r = row0 + wr * 64 + m * 16 + (lane >> 4) * 4;
            #pragma unroll
            for (int j = 0; j < 4; ++j)
                Hbf[(size_t)(r + j) * WOUT + c] = __float2bfloat16(acc[m][n][j]);
        }
    }
}

// ---------------------------------------------------------------- fused one-pass edge softmax + aggregate
// HC=256 dual-chunk: lane q owns cols [8q,8q+8) (head hA=q>>3) and
// [128+8q,128+8q+8) (head hA+2). One float4 als load per edge (hA in {0,1} ->
// cndmask select, no runtime vector indexing).
__global__ __launch_bounds__(256) void attn256_kernel(const __hip_bfloat16* __restrict__ Hm,
                                                      const int* __restrict__ off,
                                                      const int* __restrict__ ssrc,
                                                      const float* __restrict__ als,
                                                      const float* __restrict__ ald,
                                                      const float* __restrict__ bias,
                                                      __hip_bfloat16* __restrict__ Out) {
    int wid  = threadIdx.x >> 6;
    int lane = threadIdx.x & 63;
    int g    = lane >> 4;
    int q    = lane & 15;
    int d    = blockIdx.x * 16 + wid * 4 + g;
    int hA   = q >> 3;             // 0 or 1; chunk B head = hA + 2

    int e0 = off[d], e1 = off[d + 1];
    float aldA = ald[(size_t)d * 4 + hA];
    float aldB = ald[(size_t)d * 4 + hA + 2];

    float accA[8], accB[8];
    #pragma unroll
    for (int c = 0; c < 8; ++c) { accA[c] = 0.f; accB[c] = 0.f; }
    float denA = 0.f, denB = 0.f;

    int j = e0;
    for (; j + 3 < e1; j += 4) {
        int s0 = ssrc[j], s1 = ssrc[j + 1], s2 = ssrc[j + 2], s3 = ssrc[j + 3];
        const __hip_bfloat16* r0 = Hm + (size_t)s0 * 256 + q * 8;
        const __hip_bfloat16* r1 = Hm + (size_t)s1 * 256 + q * 8;
        const __hip_bfloat16* r2 = Hm + (size_t)s2 * 256 + q * 8;
        const __hip_bfloat16* r3 = Hm + (size_t)s3 * 256 + q * 8;
        bf16x8 a0 = *reinterpret_cast<const bf16x8*>(r0);
        bf16x8 b0 = *reinterpret_cast<const bf16x8*>(r0 + 128);
        bf16x8 a1 = *reinterpret_cast<const bf16x8*>(r1);
        bf16x8 b1 = *reinterpret_cast<const bf16x8*>(r1 + 128);
        bf16x8 a2 = *reinterpret_cast<const bf16x8*>(r2);
        bf16x8 b2 = *reinterpret_cast<const bf16x8*>(r2 + 128);
        bf16x8 a3 = *reinterpret_cast<const bf16x8*>(r3);
        bf16x8 b3 = *reinterpret_cast<const bf16x8*>(r3 + 128);
        float4 v0 = *reinterpret_cast<const float4*>(als + (size_t)s0 * 4);
        float4 v1 = *reinterpret_cast<const float4*>(als + (size_t)s1 * 4);
        float4 v2 = *reinterpret_cast<const float4*>(als + (size_t)s2 * 4);
        float4 v3 = *reinterpret_cast<const float4*>(als + (size_t)s3 * 4);
        float xA0 = ((hA == 0) ? v0.x : v0.y) + aldA, xB0 = ((hA == 0) ? v0.z : v0.w) + aldB;
        float xA1 = ((hA == 0) ? v1.x : v1.y) + aldA, xB1 = ((hA == 0) ? v1.z : v1.w) + aldB;
        float xA2 = ((hA == 0) ? v2.x : v2.y) + aldA, xB2 = ((hA == 0) ? v2.z : v2.w) + aldB;
        float xA3 = ((hA == 0) ? v3.x : v3.y) + aldA, xB3 = ((hA == 0) ? v3.z : v3.w) + aldB;
        xA0 = (xA0 > 0.f) ? xA0 : SLOPE * xA0;  xB0 = (xB0 > 0.f) ? xB0 : SLOPE * xB0;
        xA1 = (xA1 > 0.f) ? xA1 : SLOPE * xA1;  xB1 = (xB1 > 0.f) ? xB1 : SLOPE * xB1;
        xA2 = (xA2 > 0.f) ? xA2 : SLOPE * xA2;  xB2 = (xB2 > 0.f) ? xB2 : SLOPE * xB2;
        xA3 = (xA3 > 0.f) ? xA3 : SLOPE * xA3;  xB3 = (xB3 > 0.f) ? xB3 : SLOPE * xB3;
        float wA0 = __expf(xA0), wB0 = __expf(xB0);
        float wA1 = __expf(xA1), wB1 = __expf(xB1);
        float wA2 = __expf(xA2), wB2 = __expf(xB2);
        float wA3 = __expf(xA3), wB3 = __expf(xB3);
        denA += (wA0 + wA1) + (wA2 + wA3);
        denB += (wB0 + wB1) + (wB2 + wB3);
        #pragma unroll
        for (int c = 0; c < 8; ++c) {
            accA[c] += wA0 * bf2f((unsigned short)a0[c]) + wA1 * bf2f((unsigned short)a1[c])
                     + wA2 * bf2f((unsigned short)a2[c]) + wA3 * bf2f((unsigned short)a3[c]);
            accB[c] += wB0 * bf2f((unsigned short)b0[c]) + wB1 * bf2f((unsigned short)b1[c])
                     + wB2 * bf2f((unsigned short)b2[c]) + wB3 * bf2f((unsigned short)b3[c]);
        }
    }
    for (; j < e1; ++j) {
        int s0 = ssrc[j];
        const __hip_bfloat16* r0 = Hm + (size_t)s0 * 256 + q * 8;
        bf16x8 a0 = *reinterpret_cast<const bf16x8*>(r0);
        bf16x8 b0 = *reinterpret_cast<const bf16x8*>(r0 + 128);
        float4 v0 = *reinterpret_cast<const float4*>(als + (size_t)s0 * 4);
        float xA0 = ((hA == 0) ? v0.x : v0.y) + aldA, xB0 = ((hA == 0) ? v0.z : v0.w) + aldB;
        xA0 = (xA0 > 0.f) ? xA0 : SLOPE * xA0;  xB0 = (xB0 > 0.f) ? xB0 : SLOPE * xB0;
        float wA0 = __expf(xA0), wB0 = __expf(xB0);
        denA += wA0; denB += wB0;
        #pragma unroll
        for (int c = 0; c < 8; ++c) {
            accA[c] += wA0 * bf2f((unsigned short)a0[c]);
            accB[c] += wB0 * bf2f((unsigned short)b0[c]);
        }
    }

    float invA = 1.f / (denA + 1e-16f);
    float invB = 1.f / (denB + 1e-16f);

    float4 bA0 = *reinterpret_cast<const float4*>(bias + q * 8);
    float4 bA1 = *reinterpret_cast<const float4*>(bias + q * 8 + 4);
    float4 bB0 = *reinterpret_cast<const float4*>(bias + 128 + q * 8);
    float4 bB1 = *reinterpret_cast<const float4*>(bias + 128 + q * 8 + 4);
    __hip_bfloat16 oA[8], oB[8];
    oA[0] = __float2bfloat16(fmaxf(accA[0] * invA + bA0.x, 0.f));
    oA[1] = __float2bfloat16(fmaxf(accA[1] * invA + bA0.y, 0.f));
    oA[2] = __float2bfloat16(fmaxf(accA[2] * invA + bA0.z, 0.f));
    oA[3] = __float2bfloat16(fmaxf(accA[3] * invA + bA0.w, 0.f));
    oA[4] = __float2bfloat16(fmaxf(accA[4] * invA + bA1.x, 0.f));
    oA[5] = __float2bfloat16(fmaxf(accA[5] * invA + bA1.y, 0.f));
    oA[6] = __float2bfloat16(fmaxf(accA[6] * invA + bA1.z, 0.f));
    oA[7] = __float2bfloat16(fmaxf(accA[7] * invA + bA1.w, 0.f));
    oB[0] = __float2bfloat16(fmaxf(accB[0] * invB + bB0.x, 0.f));
    oB[1] = __float2bfloat16(fmaxf(accB[1] * invB + bB0.y, 0.f));
    oB[2] = __float2bfloat16(fmaxf(accB[2] * invB + bB0.z, 0.f));
    oB[3] = __float2bfloat16(fmaxf(accB[3] * invB + bB0.w, 0.f));
    oB[4] = __float2bfloat16(fmaxf(accB[4] * invB + bB1.x, 0.f));
    oB[5] = __float2bfloat16(fmaxf(accB[5] * invB + bB1.y, 0.f));
    oB[6] = __float2bfloat16(fmaxf(accB[6] * invB + bB1.z, 0.f));
    oB[7] = __float2bfloat16(fmaxf(accB[7] * invB + bB1.w, 0.f));
    __hip_bfloat16* op = Out + (size_t)d * 256 + q * 8;
    *reinterpret_cast<bf16x8*>(op)       = *reinterpret_cast<bf16x8*>(oA);
    *reinterpret_cast<bf16x8*>(op + 128) = *reinterpret_cast<bf16x8*>(oB);
}

// HC=128 (final layer, f32 out). CPL=8 packed.
__global__ __launch_bounds__(256) void attn128_kernel(const __hip_bfloat16* __restrict__ Hm,
                                                      const int* __restrict__ off,
                                                      const int* __restrict__ ssrc,
                                                      const float* __restrict__ als,
                                                      const float* __restrict__ ald,
                                                      const float* __restrict__ bias,
                                                      float* __restrict__ Out) {
    int wid  = threadIdx.x >> 6;
    int lane = threadIdx.x & 63;
    int g    = lane >> 4;
    int q    = lane & 15;
    int d    = blockIdx.x * 16 + wid * 4 + g;
    int head = q >> 2;

    int e0 = off[d], e1 = off[d + 1];
    float aldh = ald[(size_t)d * 4 + head];

    float acc[8];
    #pragma unroll
    for (int c = 0; c < 8; ++c) acc[c] = 0.f;
    float den = 0.f;

    int j = e0;
    for (; j + 3 < e1; j += 4) {
        int s0 = ssrc[j], s1 = ssrc[j + 1], s2 = ssrc[j + 2], s3 = ssrc[j + 3];
        bf16x8 a0 = *reinterpret_cast<const bf16x8*>(Hm + (size_t)s0 * 128 + q * 8);
        bf16x8 a1 = *reinterpret_cast<const bf16x8*>(Hm + (size_t)s1 * 128 + q * 8);
        bf16x8 a2 = *reinterpret_cast<const bf16x8*>(Hm + (size_t)s2 * 128 + q * 8);
        bf16x8 a3 = *reinterpret_cast<const bf16x8*>(Hm + (size_t)s3 * 128 + q * 8);
        float x0 = als[(size_t)s0 * 4 + head] + aldh;
        float x1 = als[(size_t)s1 * 4 + head] + aldh;
        float x2 = als[(size_t)s2 * 4 + head] + aldh;
        float x3 = als[(size_t)s3 * 4 + head] + aldh;
        x0 = (x0 > 0.f) ? x0 : SLOPE * x0;
        x1 = (x1 > 0.f) ? x1 : SLOPE * x1;
        x2 = (x2 > 0.f) ? x2 : SLOPE * x2;
        x3 = (x3 > 0.f) ? x3 : SLOPE * x3;
        float w0 = __expf(x0), w1 = __expf(x1), w2 = __expf(x2), w3 = __expf(x3);
        den += (w0 + w1) + (w2 + w3);
        #pragma unroll
        for (int c = 0; c < 8; ++c)
            acc[c] += w0 * bf2f((unsigned short)a0[c]) + w1 * bf2f((unsigned short)a1[c])
                    + w2 * bf2f((unsigned short)a2[c]) + w3 * bf2f((unsigned short)a3[c]);
    }
    for (; j < e1; ++j) {
        int s0 = ssrc[j];
        bf16x8 a0 = *reinterpret_cast<const bf16x8*>(Hm + (size_t)s0 * 128 + q * 8);
        float x0 = als[(size_t)s0 * 4 + head] + aldh;
        x0 = (x0 > 0.f) ? x0 : SLOPE * x0;
        float w0 = __expf(x0);
        den += w0;
        #pragma unroll
        for (int c = 0; c < 8; ++c) acc[c] += w0 * bf2f((unsigned short)a0[c]);
    }

    float inv = 1.f / (den + 1e-16f);
    float4 b0 = *reinterpret_cast<const float4*>(bias + q * 8);
    float4 b1 = *reinterpret_cast<const float4*>(bias + q * 8 + 4);
    float* op = Out + (size_t)d * 128 + q * 8;
    *reinterpret_cast<float4*>(op) = make_float4(
        fmaxf(acc[0] * inv + b0.x, 0.f), fmaxf(acc[1] * inv + b0.y, 0.f),
        fmaxf(acc[2] * inv + b0.z, 0.f), fmaxf(acc[3] * inv + b0.w, 0.f));
    *reinterpret_cast<float4*>(op + 4) = make_float4(
        fmaxf(acc[4] * inv + b1.x, 0.f), fmaxf(acc[5] * inv + b1.y, 0.f),
        fmaxf(acc[6] * inv + b1.z, 0.f), fmaxf(acc[7] * inv + b1.w, 0.f));
}

// ---------------------------------------------------------------- batch norm (bf16 input)
__global__ __launch_bounds__(256) void bnstats_kernel(const __hip_bfloat16* __restrict__ X,
                                                      float* __restrict__ sums) {
    int c  = threadIdx.x;
    int r0 = blockIdx.x * 200;
    float s = 0.f, q = 0.f;
    for (int r = r0; r < r0 + 200; ++r) {
        float v = bf2f(*(const unsigned short*)(X + (size_t)r * 256 + c));
        s += v; q += v * v;
    }
    atomicAdd(&sums[c], s);
    atomicAdd(&sums[256 + c], q);
}

// ---------------------------------------------------------------- launch

extern "C" void kernel_launch(void* const* d_in, const int* in_sizes, int n_in,
                              void* d_out, int out_size, void* d_ws, size_t ws_size,
                              hipStream_t stream) {
    const float* x      = (const float*)d_in[0];
    const int*   ei     = (const int*)d_in[1];
    const float* W1     = (const float*)d_in[2];
    const float* a_s1   = (const float*)d_in[3];
    const float* a_d1   = (const float*)d_in[4];
    const float* b1     = (const float*)d_in[5];
    const float* W2     = (const float*)d_in[6];
    const float* a_s2   = (const float*)d_in[7];
    const float* a_d2   = (const float*)d_in[8];
    const float* b2     = (const float*)d_in[9];
    const float* W3     = (const float*)d_in[10];
    const float* a_s3   = (const float*)d_in[11];
    const float* a_d3   = (const float*)d_in[12];
    const float* b3     = (const float*)d_in[13];
    const float* gamma1 = (const float*)d_in[14];
    const float* beta1  = (const float*)d_in[15];
    const float* gamma2 = (const float*)d_in[16];
    const float* beta2  = (const float*)d_in[17];

    char* ws = (char*)d_ws;
    size_t o = 0;
    auto alloc = [&](size_t bytes) -> void* {
        void* p = ws + o;
        o = (o + bytes + 255) & ~size_t(255);
        return p;
    };
    __hip_bfloat16*  Abf  = (__hip_bfloat16*)alloc((size_t)NP * 256 * 2);
    __hip_bfloat16*  Hbf  = (__hip_bfloat16*)alloc((size_t)NP * 256 * 2);
    __hip_bfloat16*  Xbf  = (__hip_bfloat16*)alloc((size_t)NP * 128 * 2);
    __hip_bfloat16*  WT1  = (__hip_bfloat16*)alloc((size_t)256 * 128 * 2);
    __hip_bfloat16*  WT2  = (__hip_bfloat16*)alloc((size_t)256 * 256 * 2);
    __hip_bfloat16*  WT3  = (__hip_bfloat16*)alloc((size_t)128 * 256 * 2);
    float* bb2   = (float*)alloc(256 * 4);
    float* bb3   = (float*)alloc(128 * 4);
    float* als   = (float*)alloc((size_t)NP * 4 * 4);
    float* ald   = (float*)alloc((size_t)NP * 4 * 4);
    float* sums  = (float*)alloc(1024 * 4);      // [0:512) layer1, [512:1024) layer2
    int*   off   = (int*)alloc((size_t)(NN + 1) * 4);
    int*   cur   = (int*)alloc((size_t)NN * 4);
    int*   cnt   = (int*)alloc((size_t)NN * 4);
    int*   bsum  = (int*)alloc((size_t)NBLK * 4);
    int*   bexc  = (int*)alloc((size_t)NBLK * 4);
    int*   ssrc  = (int*)alloc((size_t)ETOT * 4);
    (void)ws_size; (void)in_sizes; (void)n_in; (void)out_size;

    const int EB = (ETOT + 255) / 256;

    // --- CSR build + zero both BN sum buffers (one memset)
    hipMemsetAsync(cnt, 0, (size_t)NN * 4, stream);
    hipMemsetAsync(sums, 0, 1024 * 4, stream);
    count_kernel<<<EB, 256, 0, stream>>>(ei, cnt);
    scanA_kernel<<<NBLK, 256, 0, stream>>>(cnt, off, bsum);
    scanB_kernel<<<1, 256, 0, stream>>>(bsum, bexc, off);
    scanC_kernel<<<NBLK, 256, 0, stream>>>(bexc, off, cur);
    fill_kernel<<<EB, 256, 0, stream>>>(ei, cur, ssrc);

    // --- layer 1
    castwx_kernel<<<XB + 128, 256, 0, stream>>>(x, W1, Xbf, WT1);
    mgemm_kernel<128, 256, false><<<dim3(NP / 128, 2), 256, 0, stream>>>(
        Xbf, WT1, nullptr, a_s1, a_d1, Hbf, als, ald);
    attn256_kernel<<<NN / 16, 256, 0, stream>>>(Hbf, off, ssrc, als, ald, b1, Abf);

    bnstats_kernel<<<250, 256, 0, stream>>>(Abf, sums);
    foldw_kernel<256><<<256, 256, 0, stream>>>(W2, sums, gamma1, beta1, WT2, bb2);

    // --- layer 2 (BN folded into WT2/bb2)
    mgemm_kernel<256, 256, true><<<dim3(NP / 128, 2), 256, 0, stream>>>(
        Abf, WT2, bb2, a_s2, a_d2, Hbf, als, ald);
    attn256_kernel<<<NN / 16, 256, 0, stream>>>(Hbf, off, ssrc, als, ald, b2, Abf);

    bnstats_kernel<<<250, 256, 0, stream>>>(Abf, sums + 512);
    foldw_kernel<128><<<128, 256, 0, stream>>>(W3, sums + 512, gamma2, beta2, WT3, bb3);

    // --- layer 3 (BN folded into WT3/bb3), f32 output
    mgemm_kernel<256, 128, true><<<dim3(NP / 128, 1), 256, 0, stream>>>(
        Abf, WT3, bb3, a_s3, a_d3, Hbf, als, ald);
    attn128_kernel<<<NN / 16, 256, 0, stream>>>(Hbf, off, ssrc, als, ald, b3, (float*)d_out);
}

// Round 12
// 376.368 us; speedup vs baseline: 1.8507x; 1.0045x over previous
//
#include <hip/hip_runtime.h>
#include <hip/hip_bf16.h>

// Problem constants (fixed by the reference)
constexpr int NN   = 50000;            // nodes
constexpr int EE   = 800000;            // random edges
constexpr int ETOT = EE + NN;          // + self loops
constexpr int NP   = 50048;            // rows padded to multiple of 128 (391*128)
constexpr int NBLK = (NN + 255) / 256; // 196 scan blocks
constexpr float SLOPE  = 0.2f;
constexpr float EPS_BN = 1e-5f;

typedef __attribute__((ext_vector_type(8))) short bf16x8;
typedef __attribute__((ext_vector_type(4))) float f32x4;

__device__ inline float bf2f(unsigned short u) {
    union { unsigned int i; float f; } c; c.i = ((unsigned int)u) << 16; return c.f;
}

__device__ inline void gload16(const __hip_bfloat16* g, __hip_bfloat16* l) {
    __builtin_amdgcn_global_load_lds(
        (const __attribute__((address_space(1))) unsigned int*)g,
        (__attribute__((address_space(3))) unsigned int*)l, 16, 0, 0);
}

// ---------------------------------------------------------------- CSR build

__global__ __launch_bounds__(256) void count_kernel(const int* __restrict__ ei,
                                                    int* __restrict__ cnt) {
    int j = blockIdx.x * 256 + threadIdx.x;
    if (j >= ETOT) return;
    int dst = (j < EE) ? ei[EE + j] : (j - EE);
    atomicAdd(&cnt[dst], 1);
}

__global__ __launch_bounds__(256) void scanA_kernel(const int* __restrict__ cnt,
                                                    int* __restrict__ off,
                                                    int* __restrict__ bsum) {
    int b = blockIdx.x, t = threadIdx.x;
    int i = b * 256 + t;
    int v = (i < NN) ? cnt[i] : 0;
    int lane = t & 63, w = t >> 6;
    int x = v;
    #pragma unroll
    for (int o = 1; o < 64; o <<= 1) { int y = __shfl_up(x, o); if (lane >= o) x += y; }
    __shared__ int ws[4];
    if (lane == 63) ws[w] = x;
    __syncthreads();
    int wo = 0;
    for (int k = 0; k < w; ++k) wo += ws[k];
    int incl = x + wo;
    if (i < NN) off[i] = incl - v;
    if (t == 255) bsum[b] = incl;
}

__global__ __launch_bounds__(256) void scanB_kernel(const int* __restrict__ bsum,
                                                    int* __restrict__ bexc,
                                                    int* __restrict__ off) {
    int t = threadIdx.x;
    int v = (t < NBLK) ? bsum[t] : 0;
    int lane = t & 63, w = t >> 6;
    int x = v;
    #pragma unroll
    for (int o = 1; o < 64; o <<= 1) { int y = __shfl_up(x, o); if (lane >= o) x += y; }
    __shared__ int ws[4];
    if (lane == 63) ws[w] = x;
    __syncthreads();
    int wo = 0;
    for (int k = 0; k < w; ++k) wo += ws[k];
    int incl = x + wo;
    if (t < NBLK) bexc[t] = incl - v;
    if (t == 255) off[NN] = incl;
}

__global__ __launch_bounds__(256) void scanC_kernel(const int* __restrict__ bexc,
                                                    int* __restrict__ off,
                                                    int* __restrict__ cur) {
    int i = blockIdx.x * 256 + threadIdx.x;
    if (i >= NN) return;
    int v = off[i] + bexc[blockIdx.x];
    off[i] = v;
    cur[i] = v;
}

__global__ __launch_bounds__(256) void fill_kernel(const int* __restrict__ ei,
                                                   int* __restrict__ cursor,
                                                   int* __restrict__ ssrc) {
    int j = blockIdx.x * 256 + threadIdx.x;
    if (j >= ETOT) return;
    int src, dst;
    if (j < EE) { src = ei[j]; dst = ei[EE + j]; }
    else        { src = dst = j - EE; }
    int pos = atomicAdd(&cursor[dst], 1);
    ssrc[pos] = src;
}

// ---------------------------------------------------------------- layer-1 casts (fused)
constexpr int XB = (int)(((long)NP * 128 / 8 + 255) / 256);
__global__ __launch_bounds__(256) void castwx_kernel(const float* __restrict__ X,
                                                     const float* __restrict__ W,
                                                     __hip_bfloat16* __restrict__ Xbf,
                                                     __hip_bfloat16* __restrict__ WT) {
    int b = blockIdx.x;
    if (b < XB) {
        long e0 = ((long)b * 256 + threadIdx.x) * 8;
        if (e0 >= (long)NP * 128) return;
        int row = (int)(e0 / 128);
        __hip_bfloat16 o[8];
        if (row < NN) {
            float4 v0 = *reinterpret_cast<const float4*>(X + e0);
            float4 v1 = *reinterpret_cast<const float4*>(X + e0 + 4);
            o[0] = __float2bfloat16(v0.x); o[1] = __float2bfloat16(v0.y);
            o[2] = __float2bfloat16(v0.z); o[3] = __float2bfloat16(v0.w);
            o[4] = __float2bfloat16(v1.x); o[5] = __float2bfloat16(v1.y);
            o[6] = __float2bfloat16(v1.z); o[7] = __float2bfloat16(v1.w);
        } else {
            for (int j = 0; j < 8; ++j) o[j] = __float2bfloat16(0.f);
        }
        *reinterpret_cast<bf16x8*>(Xbf + e0) = *reinterpret_cast<bf16x8*>(o);
    } else {
        int i = (b - XB) * 256 + threadIdx.x;
        int c = i / 128, k = i % 128;
        WT[i] = __float2bfloat16(W[(size_t)k * 256 + c]);
    }
}

// fold BN (from raw sums) + transpose next-layer W; bb[c] = sum_k shift[k]*W[k][c]
template <int WOUT>
__global__ __launch_bounds__(256) void foldw_kernel(const float* __restrict__ W,
                                                    const float* __restrict__ sums,
                                                    const float* __restrict__ gamma,
                                                    const float* __restrict__ beta,
                                                    __hip_bfloat16* __restrict__ WTp,
                                                    float* __restrict__ bb) {
    int c = blockIdx.x, k = threadIdx.x;
    float mean = sums[k] / (float)NN;
    float var  = sums[256 + k] / (float)NN - mean * mean;
    float inv  = rsqrtf(var + EPS_BN);
    float sc   = gamma[k] * inv;
    float sh   = beta[k] - mean * sc;
    float w = W[(size_t)k * WOUT + c];
    WTp[(size_t)c * 256 + k] = __float2bfloat16(sc * w);
    float p = sh * w;
    #pragma unroll
    for (int o = 1; o < 64; o <<= 1) p += __shfl_xor(p, o);
    __shared__ float ps[4];
    if ((k & 63) == 0) ps[k >> 6] = p;
    __syncthreads();
    if (k == 0) bb[c] = ps[0] + ps[1] + ps[2] + ps[3];
}

// ---------------------------------------------------------------- MFMA GEMM + fused al_src/al_dst
// BK=64 via dual k-block LDS buffers (same 32-elem row stride per buffer ->
// no bank-conflict change, gload16 linear dest preserved). Halves barrier count.
template <int FIN, int WOUT, bool FOLD>
__global__ __launch_bounds__(256) void mgemm_kernel(const __hip_bfloat16* __restrict__ A,
                                                    const __hip_bfloat16* __restrict__ BT,
                                                    const float* __restrict__ bb,
                                                    const float* __restrict__ a_src,
                                                    const float* __restrict__ a_dst,
                                                    __hip_bfloat16* __restrict__ Hbf,
                                                    float* __restrict__ als,
                                                    float* __restrict__ ald) {
    __shared__ __hip_bfloat16 As[2][128 * 32];
    __shared__ __hip_bfloat16 Bs[2][128 * 32];
    int t = threadIdx.x;
    int lane = t & 63, w = t >> 6;
    int row0 = blockIdx.x * 128;
    int col0 = blockIdx.y * 128;
    int wr = w >> 1, wc = w & 1;

    f32x4 acc[4][4];
    #pragma unroll
    for (int m = 0; m < 4; ++m)
        #pragma unroll
        for (int n = 0; n < 4; ++n) acc[m][n] = (f32x4){0.f, 0.f, 0.f, 0.f};

    int srow = w * 32 + (lane >> 2);
    int sbc  = (lane & 3) * 8;
    const __hip_bfloat16* gA0 = A  + (size_t)(row0 + srow)      * FIN + sbc;
    const __hip_bfloat16* gA1 = A  + (size_t)(row0 + srow + 16) * FIN + sbc;
    const __hip_bfloat16* gB0 = BT + (size_t)(col0 + srow)      * FIN + sbc;
    const __hip_bfloat16* gB1 = BT + (size_t)(col0 + srow + 16) * FIN + sbc;
    __hip_bfloat16* lA0  = &As[0][w * 1024];
    __hip_bfloat16* lA1  = lA0 + 512;
    __hip_bfloat16* lA0b = &As[1][w * 1024];
    __hip_bfloat16* lA1b = lA0b + 512;
    __hip_bfloat16* lB0  = &Bs[0][w * 1024];
    __hip_bfloat16* lB1  = lB0 + 512;
    __hip_bfloat16* lB0b = &Bs[1][w * 1024];
    __hip_bfloat16* lB1b = lB0b + 512;

    int rA = (wr * 64 + (lane & 15)) * 32 + (lane >> 4) * 8;
    int rB = (wc * 64 + (lane & 15)) * 32 + (lane >> 4) * 8;

    for (int k0 = 0; k0 < FIN; k0 += 64) {
        gload16(gA0 + k0, lA0);
        gload16(gA1 + k0, lA1);
        gload16(gB0 + k0, lB0);
        gload16(gB1 + k0, lB1);
        gload16(gA0 + k0 + 32, lA0b);
        gload16(gA1 + k0 + 32, lA1b);
        gload16(gB0 + k0 + 32, lB0b);
        gload16(gB1 + k0 + 32, lB1b);
        __syncthreads();
        {
            bf16x8 af[4], bfr[4];
            #pragma unroll
            for (int m = 0; m < 4; ++m) af[m]  = *reinterpret_cast<const bf16x8*>(&As[0][0] + rA + m * 16 * 32);
            #pragma unroll
            for (int n = 0; n < 4; ++n) bfr[n] = *reinterpret_cast<const bf16x8*>(&Bs[0][0] + rB + n * 16 * 32);
            #pragma unroll
            for (int m = 0; m < 4; ++m)
                #pragma unroll
                for (int n = 0; n < 4; ++n)
                    acc[m][n] = __builtin_amdgcn_mfma_f32_16x16x32_bf16(af[m], bfr[n], acc[m][n], 0, 0, 0);
        }
        {
            bf16x8 af[4], bfr[4];
            #pragma unroll
            for (int m = 0; m < 4; ++m) af[m]  = *reinterpret_cast<const bf16x8*>(&As[1][0] + rA + m * 16 * 32);
            #pragma unroll
            for (int n = 0; n < 4; ++n) bfr[n] = *reinterpret_cast<const bf16x8*>(&Bs[1][0] + rB + n * 16 * 32);
            #pragma unroll
            for (int m = 0; m < 4; ++m)
                #pragma unroll
                for (int n = 0; n < 4; ++n)
                    acc[m][n] = __builtin_amdgcn_mfma_f32_16x16x32_bf16(af[m], bfr[n], acc[m][n], 0, 0, 0);
        }
        __syncthreads();
    }

    int cih = lane & 15;

    if constexpr (FOLD) {
        #pragma unroll
        for (int n = 0; n < 4; ++n) {
            float badd = bb[col0 + wc * 64 + n * 16 + cih];
            #pragma unroll
            for (int m = 0; m < 4; ++m)
                #pragma unroll
                for (int j = 0; j < 4; ++j) acc[m][n][j] += badd;
        }
    }

    float asv[4], adv[4];
    int headw = 0;
    if constexpr (WOUT == 256) {
        headw = (col0 >> 6) + wc;
        #pragma unroll
        for (int n = 0; n < 4; ++n) {
            asv[n] = a_src[headw * 64 + n * 16 + cih];
            adv[n] = a_dst[headw * 64 + n * 16 + cih];
        }
    } else {
        #pragma unroll
        for (int n = 0; n < 4; ++n) {
            int hh = wc * 2 + (n >> 1);
            asv[n] = a_src[hh * 32 + (n & 1) * 16 + cih];
            adv[n] = a_dst[hh * 32 + (n & 1) * 16 + cih];
        }
    }

    #pragma unroll
    for (int m = 0; m < 4; ++m) {
        #pragma unroll
        for (int j = 0; j < 4; ++j) {
            int r = row0 + wr * 64 + m * 16 + (lane >> 4) * 4 + j;
            if constexpr (WOUT == 256) {
                float vs = acc[m][0][j] * asv[0] + acc[m][1][j] * asv[1]
                         + acc[m][2][j] * asv[2] + acc[m][3][j] * asv[3];
                float vd = acc[m][0][j] * adv[0] + acc[m][1][j] * adv[1]
                         + acc[m][2][j] * adv[2] + acc[m][3][j] * adv[3];
                #pragma unroll
                for (int o = 1; o < 16; o <<= 1) {
                    vs += __shfl_xor(vs, o);
                    vd += __shfl_xor(vd, o);
                }
                if (cih == 0) {
                    als[(size_t)r * 4 + headw] = vs;
                    ald[(size_t)r * 4 + headw] = vd;
                }
            } else {
                float vs0 = acc[m][0][j] * asv[0] + acc[m][1][j] * asv[1];
                float vs1 = acc[m][2][j] * asv[2] + acc[m][3][j] * asv[3];
                float vd0 = acc[m][0][j] * adv[0] + acc[m][1][j] * adv[1];
                float vd1 = acc[m][2][j] * adv[2] + acc[m][3][j] * adv[3];
                #pragma unroll
                for (int o = 1; o < 16; o <<= 1) {
                    vs0 += __shfl_xor(vs0, o); vs1 += __shfl_xor(vs1, o);
                    vd0 += __shfl_xor(vd0, o); vd1 += __shfl_xor(vd1, o);
                }
                if (cih == 0) {
                    als[(size_t)r * 4 + wc * 2]     = vs0;
                    als[(size_t)r * 4 + wc * 2 + 1] = vs1;
                    ald[(size_t)r * 4 + wc * 2]     = vd0;
                    ald[(size_t)r * 4 + wc * 2 + 1] = vd1;
                }
            }
        }
    }

    #pragma unroll
    for (int n = 0; n < 4; ++n) {
        int c = col0 + wc * 64 + n * 16 + cih;
        #pragma unroll
        for (int m = 0; m < 4; ++m) {
            int r = row0 + wr * 64 + m * 16 + (lane >> 4) * 4;
            #pragma unroll
            for (int j = 0; j < 4; ++j)
                Hbf[(size_t)(r + j) * WOUT + c] = __float2bfloat16(acc[m][n][j]);
        }
    }
}

// ---------------------------------------------------------------- fused one-pass edge softmax + aggregate
// HC=256 dual-chunk: lane q owns cols [8q,8q+8) (head hA=q>>3) and
// [128+8q,128+8q+8) (head hA+2). One float4 als load per edge.
__global__ __launch_bounds__(256) void attn256_kernel(const __hip_bfloat16* __restrict__ Hm,
                                                      const int* __restrict__ off,
                                                      const int* __restrict__ ssrc,
                                                      const float* __restrict__ als,
                                                      const float* __restrict__ ald,
                                                      const float* __restrict__ bias,
                                                      __hip_bfloat16* __restrict__ Out) {
    int wid  = threadIdx.x >> 6;
    int lane = threadIdx.x & 63;
    int g    = lane >> 4;
    int q    = lane & 15;
    int d    = blockIdx.x * 16 + wid * 4 + g;
    int hA   = q >> 3;             // 0 or 1; chunk B head = hA + 2

    int e0 = off[d], e1 = off[d + 1];
    float aldA = ald[(size_t)d * 4 + hA];
    float aldB = ald[(size_t)d * 4 + hA + 2];

    float accA[8], accB[8];
    #pragma unroll
    for (int c = 0; c < 8; ++c) { accA[c] = 0.f; accB[c] = 0.f; }
    float denA = 0.f, denB = 0.f;

    int j = e0;
    for (; j + 3 < e1; j += 4) {
        int s0 = ssrc[j], s1 = ssrc[j + 1], s2 = ssrc[j + 2], s3 = ssrc[j + 3];
        const __hip_bfloat16* r0 = Hm + (size_t)s0 * 256 + q * 8;
        const __hip_bfloat16* r1 = Hm + (size_t)s1 * 256 + q * 8;
        const __hip_bfloat16* r2 = Hm + (size_t)s2 * 256 + q * 8;
        const __hip_bfloat16* r3 = Hm + (size_t)s3 * 256 + q * 8;
        bf16x8 a0 = *reinterpret_cast<const bf16x8*>(r0);
        bf16x8 b0 = *reinterpret_cast<const bf16x8*>(r0 + 128);
        bf16x8 a1 = *reinterpret_cast<const bf16x8*>(r1);
        bf16x8 b1 = *reinterpret_cast<const bf16x8*>(r1 + 128);
        bf16x8 a2 = *reinterpret_cast<const bf16x8*>(r2);
        bf16x8 b2 = *reinterpret_cast<const bf16x8*>(r2 + 128);
        bf16x8 a3 = *reinterpret_cast<const bf16x8*>(r3);
        bf16x8 b3 = *reinterpret_cast<const bf16x8*>(r3 + 128);
        float4 v0 = *reinterpret_cast<const float4*>(als + (size_t)s0 * 4);
        float4 v1 = *reinterpret_cast<const float4*>(als + (size_t)s1 * 4);
        float4 v2 = *reinterpret_cast<const float4*>(als + (size_t)s2 * 4);
        float4 v3 = *reinterpret_cast<const float4*>(als + (size_t)s3 * 4);
        float xA0 = ((hA == 0) ? v0.x : v0.y) + aldA, xB0 = ((hA == 0) ? v0.z : v0.w) + aldB;
        float xA1 = ((hA == 0) ? v1.x : v1.y) + aldA, xB1 = ((hA == 0) ? v1.z : v1.w) + aldB;
        float xA2 = ((hA == 0) ? v2.x : v2.y) + aldA, xB2 = ((hA == 0) ? v2.z : v2.w) + aldB;
        float xA3 = ((hA == 0) ? v3.x : v3.y) + aldA, xB3 = ((hA == 0) ? v3.z : v3.w) + aldB;
        xA0 = (xA0 > 0.f) ? xA0 : SLOPE * xA0;  xB0 = (xB0 > 0.f) ? xB0 : SLOPE * xB0;
        xA1 = (xA1 > 0.f) ? xA1 : SLOPE * xA1;  xB1 = (xB1 > 0.f) ? xB1 : SLOPE * xB1;
        xA2 = (xA2 > 0.f) ? xA2 : SLOPE * xA2;  xB2 = (xB2 > 0.f) ? xB2 : SLOPE * xB2;
        xA3 = (xA3 > 0.f) ? xA3 : SLOPE * xA3;  xB3 = (xB3 > 0.f) ? xB3 : SLOPE * xB3;
        float wA0 = __expf(xA0), wB0 = __expf(xB0);
        float wA1 = __expf(xA1), wB1 = __expf(xB1);
        float wA2 = __expf(xA2), wB2 = __expf(xB2);
        float wA3 = __expf(xA3), wB3 = __expf(xB3);
        denA += (wA0 + wA1) + (wA2 + wA3);
        denB += (wB0 + wB1) + (wB2 + wB3);
        #pragma unroll
        for (int c = 0; c < 8; ++c) {
            accA[c] += wA0 * bf2f((unsigned short)a0[c]) + wA1 * bf2f((unsigned short)a1[c])
                     + wA2 * bf2f((unsigned short)a2[c]) + wA3 * bf2f((unsigned short)a3[c]);
            accB[c] += wB0 * bf2f((unsigned short)b0[c]) + wB1 * bf2f((unsigned short)b1[c])
                     + wB2 * bf2f((unsigned short)b2[c]) + wB3 * bf2f((unsigned short)b3[c]);
        }
    }
    for (; j < e1; ++j) {
        int s0 = ssrc[j];
        const __hip_bfloat16* r0 = Hm + (size_t)s0 * 256 + q * 8;
        bf16x8 a0 = *reinterpret_cast<const bf16x8*>(r0);
        bf16x8 b0 = *reinterpret_cast<const bf16x8*>(r0 + 128);
        float4 v0 = *reinterpret_cast<const float4*>(als + (size_t)s0 * 4);
        float xA0 = ((hA == 0) ? v0.x : v0.y) + aldA, xB0 = ((hA == 0) ? v0.z : v0.w) + aldB;
        xA0 = (xA0 > 0.f) ? xA0 : SLOPE * xA0;  xB0 = (xB0 > 0.f) ? xB0 : SLOPE * xB0;
        float wA0 = __expf(xA0), wB0 = __expf(xB0);
        denA += wA0; denB += wB0;
        #pragma unroll
        for (int c = 0; c < 8; ++c) {
            accA[c] += wA0 * bf2f((unsigned short)a0[c]);
            accB[c] += wB0 * bf2f((unsigned short)b0[c]);
        }
    }

    float invA = 1.f / (denA + 1e-16f);
    float invB = 1.f / (denB + 1e-16f);

    float4 bA0 = *reinterpret_cast<const float4*>(bias + q * 8);
    float4 bA1 = *reinterpret_cast<const float4*>(bias + q * 8 + 4);
    float4 bB0 = *reinterpret_cast<const float4*>(bias + 128 + q * 8);
    float4 bB1 = *reinterpret_cast<const float4*>(bias + 128 + q * 8 + 4);
    __hip_bfloat16 oA[8], oB[8];
    oA[0] = __float2bfloat16(fmaxf(accA[0] * invA + bA0.x, 0.f));
    oA[1] = __float2bfloat16(fmaxf(accA[1] * invA + bA0.y, 0.f));
    oA[2] = __float2bfloat16(fmaxf(accA[2] * invA + bA0.z, 0.f));
    oA[3] = __float2bfloat16(fmaxf(accA[3] * invA + bA0.w, 0.f));
    oA[4] = __float2bfloat16(fmaxf(accA[4] * invA + bA1.x, 0.f));
    oA[5] = __float2bfloat16(fmaxf(accA[5] * invA + bA1.y, 0.f));
    oA[6] = __float2bfloat16(fmaxf(accA[6] * invA + bA1.z, 0.f));
    oA[7] = __float2bfloat16(fmaxf(accA[7] * invA + bA1.w, 0.f));
    oB[0] = __float2bfloat16(fmaxf(accB[0] * invB + bB0.x, 0.f));
    oB[1] = __float2bfloat16(fmaxf(accB[1] * invB + bB0.y, 0.f));
    oB[2] = __float2bfloat16(fmaxf(accB[2] * invB + bB0.z, 0.f));
    oB[3] = __float2bfloat16(fmaxf(accB[3] * invB + bB0.w, 0.f));
    oB[4] = __float2bfloat16(fmaxf(accB[4] * invB + bB1.x, 0.f));
    oB[5] = __float2bfloat16(fmaxf(accB[5] * invB + bB1.y, 0.f));
    oB[6] = __float2bfloat16(fmaxf(accB[6] * invB + bB1.z, 0.f));
    oB[7] = __float2bfloat16(fmaxf(accB[7] * invB + bB1.w, 0.f));
    __hip_bfloat16* op = Out + (size_t)d * 256 + q * 8;
    *reinterpret_cast<bf16x8*>(op)       = *reinterpret_cast<bf16x8*>(oA);
    *reinterpret_cast<bf16x8*>(op + 128) = *reinterpret_cast<bf16x8*>(oB);
}

// HC=128 (final layer, f32 out). CPL=8 packed.
__global__ __launch_bounds__(256) void attn128_kernel(const __hip_bfloat16* __restrict__ Hm,
                                                      const int* __restrict__ off,
                                                      const int* __restrict__ ssrc,
                                                      const float* __restrict__ als,
                                                      const float* __restrict__ ald,
                                                      const float* __restrict__ bias,
                                                      float* __restrict__ Out) {
    int wid  = threadIdx.x >> 6;
    int lane = threadIdx.x & 63;
    int g    = lane >> 4;
    int q    = lane & 15;
    int d    = blockIdx.x * 16 + wid * 4 + g;
    int head = q >> 2;

    int e0 = off[d], e1 = off[d + 1];
    float aldh = ald[(size_t)d * 4 + head];

    float acc[8];
    #pragma unroll
    for (int c = 0; c < 8; ++c) acc[c] = 0.f;
    float den = 0.f;

    int j = e0;
    for (; j + 3 < e1; j += 4) {
        int s0 = ssrc[j], s1 = ssrc[j + 1], s2 = ssrc[j + 2], s3 = ssrc[j + 3];
        bf16x8 a0 = *reinterpret_cast<const bf16x8*>(Hm + (size_t)s0 * 128 + q * 8);
        bf16x8 a1 = *reinterpret_cast<const bf16x8*>(Hm + (size_t)s1 * 128 + q * 8);
        bf16x8 a2 = *reinterpret_cast<const bf16x8*>(Hm + (size_t)s2 * 128 + q * 8);
        bf16x8 a3 = *reinterpret_cast<const bf16x8*>(Hm + (size_t)s3 * 128 + q * 8);
        float x0 = als[(size_t)s0 * 4 + head] + aldh;
        float x1 = als[(size_t)s1 * 4 + head] + aldh;
        float x2 = als[(size_t)s2 * 4 + head] + aldh;
        float x3 = als[(size_t)s3 * 4 + head] + aldh;
        x0 = (x0 > 0.f) ? x0 : SLOPE * x0;
        x1 = (x1 > 0.f) ? x1 : SLOPE * x1;
        x2 = (x2 > 0.f) ? x2 : SLOPE * x2;
        x3 = (x3 > 0.f) ? x3 : SLOPE * x3;
        float w0 = __expf(x0), w1 = __expf(x1), w2 = __expf(x2), w3 = __expf(x3);
        den += (w0 + w1) + (w2 + w3);
        #pragma unroll
        for (int c = 0; c < 8; ++c)
            acc[c] += w0 * bf2f((unsigned short)a0[c]) + w1 * bf2f((unsigned short)a1[c])
                    + w2 * bf2f((unsigned short)a2[c]) + w3 * bf2f((unsigned short)a3[c]);
    }
    for (; j < e1; ++j) {
        int s0 = ssrc[j];
        bf16x8 a0 = *reinterpret_cast<const bf16x8*>(Hm + (size_t)s0 * 128 + q * 8);
        float x0 = als[(size_t)s0 * 4 + head] + aldh;
        x0 = (x0 > 0.f) ? x0 : SLOPE * x0;
        float w0 = __expf(x0);
        den += w0;
        #pragma unroll
        for (int c = 0; c < 8; ++c) acc[c] += w0 * bf2f((unsigned short)a0[c]);
    }

    float inv = 1.f / (den + 1e-16f);
    float4 b0 = *reinterpret_cast<const float4*>(bias + q * 8);
    float4 b1 = *reinterpret_cast<const float4*>(bias + q * 8 + 4);
    float* op = Out + (size_t)d * 128 + q * 8;
    *reinterpret_cast<float4*>(op) = make_float4(
        fmaxf(acc[0] * inv + b0.x, 0.f), fmaxf(acc[1] * inv + b0.y, 0.f),
        fmaxf(acc[2] * inv + b0.z, 0.f), fmaxf(acc[3] * inv + b0.w, 0.f));
    *reinterpret_cast<float4*>(op + 4) = make_float4(
        fmaxf(acc[4] * inv + b1.x, 0.f), fmaxf(acc[5] * inv + b1.y, 0.f),
        fmaxf(acc[6] * inv + b1.z, 0.f), fmaxf(acc[7] * inv + b1.w, 0.f));
}

// ---------------------------------------------------------------- batch norm (bf16 input)
__global__ __launch_bounds__(256) void bnstats_kernel(const __hip_bfloat16* __restrict__ X,
                                                      float* __restrict__ sums) {
    int c  = threadIdx.x;
    int r0 = blockIdx.x * 200;
    float s = 0.f, q = 0.f;
    for (int r = r0; r < r0 + 200; ++r) {
        float v = bf2f(*(const unsigned short*)(X + (size_t)r * 256 + c));
        s += v; q += v * v;
    }
    atomicAdd(&sums[c], s);
    atomicAdd(&sums[256 + c], q);
}

// ---------------------------------------------------------------- launch

extern "C" void kernel_launch(void* const* d_in, const int* in_sizes, int n_in,
                              void* d_out, int out_size, void* d_ws, size_t ws_size,
                              hipStream_t stream) {
    const float* x      = (const float*)d_in[0];
    const int*   ei     = (const int*)d_in[1];
    const float* W1     = (const float*)d_in[2];
    const float* a_s1   = (const float*)d_in[3];
    const float* a_d1   = (const float*)d_in[4];
    const float* b1     = (const float*)d_in[5];
    const float* W2     = (const float*)d_in[6];
    const float* a_s2   = (const float*)d_in[7];
    const float* a_d2   = (const float*)d_in[8];
    const float* b2     = (const float*)d_in[9];
    const float* W3     = (const float*)d_in[10];
    const float* a_s3   = (const float*)d_in[11];
    const float* a_d3   = (const float*)d_in[12];
    const float* b3     = (const float*)d_in[13];
    const float* gamma1 = (const float*)d_in[14];
    const float* beta1  = (const float*)d_in[15];
    const float* gamma2 = (const float*)d_in[16];
    const float* beta2  = (const float*)d_in[17];

    char* ws = (char*)d_ws;
    size_t o = 0;
    auto alloc = [&](size_t bytes) -> void* {
        void* p = ws + o;
        o = (o + bytes + 255) & ~size_t(255);
        return p;
    };
    __hip_bfloat16*  Abf  = (__hip_bfloat16*)alloc((size_t)NP * 256 * 2);
    __hip_bfloat16*  Hbf  = (__hip_bfloat16*)alloc((size_t)NP * 256 * 2);
    __hip_bfloat16*  Xbf  = (__hip_bfloat16*)alloc((size_t)NP * 128 * 2);
    __hip_bfloat16*  WT1  = (__hip_bfloat16*)alloc((size_t)256 * 128 * 2);
    __hip_bfloat16*  WT2  = (__hip_bfloat16*)alloc((size_t)256 * 256 * 2);
    __hip_bfloat16*  WT3  = (__hip_bfloat16*)alloc((size_t)128 * 256 * 2);
    float* bb2   = (float*)alloc(256 * 4);
    float* bb3   = (float*)alloc(128 * 4);
    float* als   = (float*)alloc((size_t)NP * 4 * 4);
    float* ald   = (float*)alloc((size_t)NP * 4 * 4);
    float* sums  = (float*)alloc(1024 * 4);      // [0:512) layer1, [512:1024) layer2
    int*   off   = (int*)alloc((size_t)(NN + 1) * 4);
    int*   cur   = (int*)alloc((size_t)NN * 4);
    int*   cnt   = (int*)alloc((size_t)NN * 4);
    int*   bsum  = (int*)alloc((size_t)NBLK * 4);
    int*   bexc  = (int*)alloc((size_t)NBLK * 4);
    int*   ssrc  = (int*)alloc((size_t)ETOT * 4);
    (void)ws_size; (void)in_sizes; (void)n_in; (void)out_size;

    const int EB = (ETOT + 255) / 256;

    // --- CSR build + zero both BN sum buffers (one memset)
    hipMemsetAsync(cnt, 0, (size_t)NN * 4, stream);
    hipMemsetAsync(sums, 0, 1024 * 4, stream);
    count_kernel<<<EB, 256, 0, stream>>>(ei, cnt);
    scanA_kernel<<<NBLK, 256, 0, stream>>>(cnt, off, bsum);
    scanB_kernel<<<1, 256, 0, stream>>>(bsum, bexc, off);
    scanC_kernel<<<NBLK, 256, 0, stream>>>(bexc, off, cur);
    fill_kernel<<<EB, 256, 0, stream>>>(ei, cur, ssrc);

    // --- layer 1
    castwx_kernel<<<XB + 128, 256, 0, stream>>>(x, W1, Xbf, WT1);
    mgemm_kernel<128, 256, false><<<dim3(NP / 128, 2), 256, 0, stream>>>(
        Xbf, WT1, nullptr, a_s1, a_d1, Hbf, als, ald);
    attn256_kernel<<<NN / 16, 256, 0, stream>>>(Hbf, off, ssrc, als, ald, b1, Abf);

    bnstats_kernel<<<250, 256, 0, stream>>>(Abf, sums);
    foldw_kernel<256><<<256, 256, 0, stream>>>(W2, sums, gamma1, beta1, WT2, bb2);

    // --- layer 2 (BN folded into WT2/bb2)
    mgemm_kernel<256, 256, true><<<dim3(NP / 128, 2), 256, 0, stream>>>(
        Abf, WT2, bb2, a_s2, a_d2, Hbf, als, ald);
    attn256_kernel<<<NN / 16, 256, 0, stream>>>(Hbf, off, ssrc, als, ald, b2, Abf);

    bnstats_kernel<<<250, 256, 0, stream>>>(Abf, sums + 512);
    foldw_kernel<128><<<128, 256, 0, stream>>>(W3, sums + 512, gamma2, beta2, WT3, bb3);

    // --- layer 3 (BN folded into WT3/bb3), f32 output
    mgemm_kernel<256, 128, true><<<dim3(NP / 128, 1), 256, 0, stream>>>(
        Abf, WT3, bb3, a_s3, a_d3, Hbf, als, ald);
    attn128_kernel<<<NN / 16, 256, 0, stream>>>(Hbf, off, ssrc, als, ald, b3, (float*)d_out);
}